// Round 6
// baseline (1463.378 us; speedup 1.0000x reference)
//
#include <hip/hip_runtime.h>
#include <hip/hip_bf16.h>

#define NN   100000
#define EE   1600000
#define DIN  128
#define HH   64
#define DEA  8
#define NCLS 2
#define NPW  4                    // nodes per wave in encode/nodehead
#define BSZ  240                  // dst nodes per bucket
#define NBUCK ((NN + BSZ - 1) / BSZ)   // 417

typedef __hip_bfloat16 bf16;

// unpack uint = two packed bf16 (lo = low 16 bits, hi = high 16 bits)
__device__ __forceinline__ void bf2x(unsigned u, float& lo, float& hi) {
    union { unsigned i; float f; } a, b;
    a.i = u << 16; b.i = u & 0xffff0000u;
    lo = a.f; hi = b.f;
}

// ---------- K2: h = relu(x@W_enc+b); hg = h@W_gat (bf16); s_src/s_dst = hg . a ----------
__global__ __launch_bounds__(256) void k_encode(
        const float* __restrict__ x,
        const float* __restrict__ W_enc, const float* __restrict__ b_enc,
        const float* __restrict__ W_gat,
        const float* __restrict__ a_src, const float* __restrict__ a_dst,
        bf16* __restrict__ hg, float* __restrict__ s_src, float* __restrict__ s_dst) {
    __shared__ float wenc[DIN * HH];       // 32 KB
    __shared__ float wgat[HH * HH];        // 16 KB
    __shared__ float hbuf[16][HH];         // 4 KB
    int tid = threadIdx.x;
    for (int i = tid; i < DIN * HH; i += 256) wenc[i] = W_enc[i];
    for (int i = tid; i < HH * HH; i += 256) wgat[i] = W_gat[i];
    int lane = tid & 63;
    int wv = __builtin_amdgcn_readfirstlane(tid >> 6);
    float biasl = b_enc[lane], avsl = a_src[lane], avdl = a_dst[lane];
    __syncthreads();
    for (int base = blockIdx.x * 16; base < NN; base += gridDim.x * 16) {
        int n0 = base + wv * NPW;
        const float* xr = x + (size_t)n0 * DIN;   // wave-uniform
        float h0 = biasl, h1 = biasl, h2 = biasl, h3 = biasl;
        #pragma unroll 4
        for (int d = 0; d < DIN; d++) {
            float w = wenc[d * HH + lane];
            h0 = fmaf(xr[d], w, h0);
            h1 = fmaf(xr[DIN + d], w, h1);
            h2 = fmaf(xr[2 * DIN + d], w, h2);
            h3 = fmaf(xr[3 * DIN + d], w, h3);
        }
        hbuf[wv * NPW + 0][lane] = fmaxf(h0, 0.f);
        hbuf[wv * NPW + 1][lane] = fmaxf(h1, 0.f);
        hbuf[wv * NPW + 2][lane] = fmaxf(h2, 0.f);
        hbuf[wv * NPW + 3][lane] = fmaxf(h3, 0.f);
        __syncthreads();
        float g[NPW] = {0.f, 0.f, 0.f, 0.f};
        #pragma unroll 4
        for (int k = 0; k < HH; k++) {
            float w = wgat[k * HH + lane];
            #pragma unroll
            for (int j = 0; j < NPW; j++) g[j] = fmaf(hbuf[wv * NPW + j][k], w, g[j]);
        }
        #pragma unroll
        for (int j = 0; j < NPW; j++) {
            hg[(size_t)(n0 + j) * HH + lane] = __float2bfloat16(g[j]);
            float ps = g[j] * avsl, pd = g[j] * avdl;
            #pragma unroll
            for (int off = 32; off; off >>= 1) {
                ps += __shfl_xor(ps, off);
                pd += __shfl_xor(pd, off);
            }
            if (lane == 0) { s_src[n0 + j] = ps; s_dst[n0 + j] = pd; }
        }
        __syncthreads();
    }
}

// ---------- B1: bucket histogram (LDS-staged) ----------
__global__ __launch_bounds__(256) void k_bhist(const int* __restrict__ dst,
                                               int* __restrict__ bcnt) {
    __shared__ int h[NBUCK];
    int tid = threadIdx.x;
    for (int i = tid; i < NBUCK; i += 256) h[i] = 0;
    __syncthreads();
    for (int e = blockIdx.x * 256 + tid; e < EE; e += gridDim.x * 256)
        atomicAdd(&h[dst[e] / BSZ], 1);
    __syncthreads();
    for (int i = tid; i < NBUCK; i += 256) {
        int v = h[i];
        if (v) atomicAdd(&bcnt[i], v);
    }
}

// ---------- B2: scan bucket counts -> bbase (exclusive), bcur = bbase ----------
__global__ void k_bscan(const int* __restrict__ bcnt,
                        int* __restrict__ bbase, int* __restrict__ bcur) {
    __shared__ int sm[512];
    int t = threadIdx.x;
    int v = (t < NBUCK) ? bcnt[t] : 0;
    sm[t] = v;
    __syncthreads();
    for (int s = 1; s < 512; s <<= 1) {
        int add = (t >= s) ? sm[t - s] : 0;
        __syncthreads();
        sm[t] += add;
        __syncthreads();
    }
    if (t < NBUCK) {
        int base = sm[t] - v;
        bbase[t] = base;
        bcur[t]  = base;
    }
}

// ---------- B3: scatter packed (dl<<24 | src) into bucket regions ----------
__global__ void k_bscatter(const int* __restrict__ src, const int* __restrict__ dst,
                           int* bcur, unsigned* __restrict__ ebuf) {
    int e = blockIdx.x * blockDim.x + threadIdx.x;
    if (e >= EE) return;
    int dv = dst[e], sv = src[e];
    int b  = dv / BSZ;
    int dl = dv - b * BSZ;
    int pos = atomicAdd(&bcur[b], 1);
    ebuf[pos] = ((unsigned)dl << 24) | (unsigned)sv;
}

// ---------- B4: per-bucket softmax+agg into LDS accumulators ----------
// 512 threads = 64 groups of 8 lanes; group owns one edge/iter, lane owns 8 dims.
// acc row stride 65 so bank = (dl + 8r + j) % 32 -> dl randomizes banks.
__global__ __launch_bounds__(512) void k_bagg(
        const unsigned* __restrict__ ebuf,
        const int* __restrict__ bbase, const int* __restrict__ bcur,
        const float* __restrict__ s_src, const float* __restrict__ s_dst,
        const bf16* __restrict__ hg, float* __restrict__ agg) {
    __shared__ float acc[BSZ * 65];   // 62400 B
    __shared__ float den[BSZ];        //   960 B
    int tid = threadIdx.x;
    int b = blockIdx.x;
    int node0 = b * BSZ;
    for (int i = tid; i < BSZ * 65; i += 512) acc[i] = 0.f;
    for (int i = tid; i < BSZ; i += 512) den[i] = 0.f;
    __syncthreads();
    int rs = bbase[b], re = bcur[b];
    int lane8 = tid & 7, gid = tid >> 3;
    for (int i = rs + gid; i < re; i += 64) {
        unsigned p = ebuf[i];
        int sv = p & 0xFFFFFF;
        int dl = p >> 24;
        float s = s_src[sv] + s_dst[node0 + dl];
        s = (s >= 0.f) ? s : 0.2f * s;        // leaky_relu 0.2
        float ex = __expf(s);                  // m=0 shift: exact (softmax shift-invariant)
        uint4 u = *(const uint4*)&hg[(size_t)sv * HH + lane8 * 8];
        float f0, f1, f2, f3, f4, f5, f6, f7;
        bf2x(u.x, f0, f1); bf2x(u.y, f2, f3);
        bf2x(u.z, f4, f5); bf2x(u.w, f6, f7);
        float* ap = &acc[dl * 65 + lane8 * 8];
        atomicAdd(ap + 0, ex * f0); atomicAdd(ap + 1, ex * f1);
        atomicAdd(ap + 2, ex * f2); atomicAdd(ap + 3, ex * f3);
        atomicAdd(ap + 4, ex * f4); atomicAdd(ap + 5, ex * f5);
        atomicAdd(ap + 6, ex * f6); atomicAdd(ap + 7, ex * f7);
        if (lane8 == 0) atomicAdd(&den[dl], ex);
    }
    __syncthreads();
    for (int idx = tid; idx < BSZ * HH; idx += 512) {
        int dl = idx >> 6, d = idx & 63;
        int node = node0 + dl;
        if (node < NN)
            agg[(size_t)node * HH + d] = acc[dl * 65 + d] / (den[dl] + 1e-9f);
    }
}

// ---------- K7: xc = relu(agg); node head; bf16 p_src/p_dst partials ----------
// p_src aliases hg (bf16, same indexing; hg dead after k_bagg). p_dst separate.
__global__ __launch_bounds__(256) void k_nodehead(
        const float* __restrict__ agg,
        const float* __restrict__ Wn1, const float* __restrict__ bn1,
        const float* __restrict__ Wn2, const float* __restrict__ bn2,
        const float* __restrict__ We1,
        bf16* __restrict__ p_src, bf16* __restrict__ p_dst, float* __restrict__ out_node) {
    __shared__ float wn1[HH * HH];     // 16 KB
    __shared__ float we1s[HH * HH];    // 16 KB
    __shared__ float we1d[HH * HH];    // 16 KB
    __shared__ float xbuf[16][HH];     // 4 KB
    int tid = threadIdx.x;
    for (int i = tid; i < HH * HH; i += 256) {
        wn1[i]  = Wn1[i];
        we1s[i] = We1[i];
        we1d[i] = We1[HH * HH + i];
    }
    int lane = tid & 63;
    int wv = __builtin_amdgcn_readfirstlane(tid >> 6);
    float bn1l = bn1[lane];
    float wn2a = Wn2[lane * NCLS + 0], wn2b = Wn2[lane * NCLS + 1];
    float bn20 = bn2[0], bn21 = bn2[1];
    __syncthreads();
    for (int base = blockIdx.x * 16; base < NN; base += gridDim.x * 16) {
        int n0 = base + wv * NPW;
        #pragma unroll
        for (int j = 0; j < NPW; j++)
            xbuf[wv * NPW + j][lane] = fmaxf(agg[(size_t)(n0 + j) * HH + lane], 0.f);
        __syncthreads();
        float tn[NPW], ps[NPW], pd[NPW];
        #pragma unroll
        for (int j = 0; j < NPW; j++) { tn[j] = bn1l; ps[j] = 0.f; pd[j] = 0.f; }
        #pragma unroll 4
        for (int k = 0; k < HH; k++) {
            float w1 = wn1[k * HH + lane];
            float ws = we1s[k * HH + lane];
            float wd = we1d[k * HH + lane];
            #pragma unroll
            for (int j = 0; j < NPW; j++) {
                float xv = xbuf[wv * NPW + j][k];
                tn[j] = fmaf(xv, w1, tn[j]);
                ps[j] = fmaf(xv, ws, ps[j]);
                pd[j] = fmaf(xv, wd, pd[j]);
            }
        }
        #pragma unroll
        for (int j = 0; j < NPW; j++) {
            int node = n0 + j;
            p_src[(size_t)node * HH + lane] = __float2bfloat16(ps[j]);
            p_dst[(size_t)node * HH + lane] = __float2bfloat16(pd[j]);
            float r = fmaxf(tn[j], 0.f);
            float l0 = r * wn2a, l1 = r * wn2b;
            #pragma unroll
            for (int off = 32; off; off >>= 1) {
                l0 += __shfl_xor(l0, off);
                l1 += __shfl_xor(l1, off);
            }
            if (lane == 0)
                *(float2*)&out_node[(size_t)node * NCLS] = make_float2(l0 + bn20, l1 + bn21);
        }
        __syncthreads();
    }
}

// ---------- K8: edge head. 16 lanes per edge-pair (2 edges/group/iter), weights in regs.
__global__ __launch_bounds__(256) void k_edgehead(
        const int* __restrict__ src, const int* __restrict__ dst,
        const float* __restrict__ edge_attr,
        const bf16* __restrict__ p_src, const bf16* __restrict__ p_dst,
        const float* __restrict__ We1, const float* __restrict__ be1,
        const float* __restrict__ We2, const float* __restrict__ be2,
        float* __restrict__ out_edge) {
    int tid = threadIdx.x;
    int lane16 = tid & 15;
    int grp    = (tid & 63) >> 4;
    int wave   = tid >> 6;
    float w1a[DEA][4], w2c0[4], w2c1[4], b1v[4];
    #pragma unroll
    for (int d = 0; d < DEA; d++) {
        float4 v = *(const float4*)&We1[(2 * HH + d) * HH + lane16 * 4];
        w1a[d][0] = v.x; w1a[d][1] = v.y; w1a[d][2] = v.z; w1a[d][3] = v.w;
    }
    float4 bv = *(const float4*)&be1[lane16 * 4];
    b1v[0] = bv.x; b1v[1] = bv.y; b1v[2] = bv.z; b1v[3] = bv.w;
    #pragma unroll
    for (int j = 0; j < 4; j++) {
        w2c0[j] = We2[(lane16 * 4 + j) * NCLS + 0];
        w2c1[j] = We2[(lane16 * 4 + j) * NCLS + 1];
    }
    float be20 = be2[0], be21 = be2[1];

    int stride = gridDim.x * 32;   // 32 edges per block-iteration
    for (int e = blockIdx.x * 32 + wave * 8 + grp * 2; e < EE; e += stride) {
        int ea = e, eb = e + 1;
        int sva = src[ea], dva = dst[ea];
        int svb = src[eb], dvb = dst[eb];
        uint2 usa = *(const uint2*)&p_src[(size_t)sva * HH + lane16 * 4];
        uint2 uda = *(const uint2*)&p_dst[(size_t)dva * HH + lane16 * 4];
        uint2 usb = *(const uint2*)&p_src[(size_t)svb * HH + lane16 * 4];
        uint2 udb = *(const uint2*)&p_dst[(size_t)dvb * HH + lane16 * 4];
        float4 aa0 = *(const float4*)&edge_attr[(size_t)ea * DEA];
        float4 aa1 = *(const float4*)&edge_attr[(size_t)ea * DEA + 4];
        float4 ab0 = *(const float4*)&edge_attr[(size_t)eb * DEA];
        float4 ab1 = *(const float4*)&edge_attr[(size_t)eb * DEA + 4];
        float ava[DEA] = {aa0.x, aa0.y, aa0.z, aa0.w, aa1.x, aa1.y, aa1.z, aa1.w};
        float avb[DEA] = {ab0.x, ab0.y, ab0.z, ab0.w, ab1.x, ab1.y, ab1.z, ab1.w};
        float sa0, sa1, sa2, sa3, da0, da1, da2, da3;
        float sb0, sb1, sb2, sb3, db0, db1, db2, db3;
        bf2x(usa.x, sa0, sa1); bf2x(usa.y, sa2, sa3);
        bf2x(uda.x, da0, da1); bf2x(uda.y, da2, da3);
        bf2x(usb.x, sb0, sb1); bf2x(usb.y, sb2, sb3);
        bf2x(udb.x, db0, db1); bf2x(udb.y, db2, db3);
        float ta[4] = {sa0 + da0 + b1v[0], sa1 + da1 + b1v[1],
                       sa2 + da2 + b1v[2], sa3 + da3 + b1v[3]};
        float tb[4] = {sb0 + db0 + b1v[0], sb1 + db1 + b1v[1],
                       sb2 + db2 + b1v[2], sb3 + db3 + b1v[3]};
        float l0a = 0.f, l1a = 0.f, l0b = 0.f, l1b = 0.f;
        #pragma unroll
        for (int j = 0; j < 4; j++) {
            #pragma unroll
            for (int d = 0; d < DEA; d++) {
                ta[j] = fmaf(ava[d], w1a[d][j], ta[j]);
                tb[j] = fmaf(avb[d], w1a[d][j], tb[j]);
            }
            float ra = fmaxf(ta[j], 0.f), rb = fmaxf(tb[j], 0.f);
            l0a = fmaf(ra, w2c0[j], l0a); l1a = fmaf(ra, w2c1[j], l1a);
            l0b = fmaf(rb, w2c0[j], l0b); l1b = fmaf(rb, w2c1[j], l1b);
        }
        #pragma unroll
        for (int off = 8; off; off >>= 1) {
            l0a += __shfl_xor(l0a, off); l1a += __shfl_xor(l1a, off);
            l0b += __shfl_xor(l0b, off); l1b += __shfl_xor(l1b, off);
        }
        if (lane16 == 0) {
            *(float2*)&out_edge[(size_t)ea * NCLS] = make_float2(l0a + be20, l1a + be21);
            *(float2*)&out_edge[(size_t)eb * NCLS] = make_float2(l0b + be20, l1b + be21);
        }
    }
}

extern "C" void kernel_launch(void* const* d_in, const int* in_sizes, int n_in,
                              void* d_out, int out_size, void* d_ws, size_t ws_size,
                              hipStream_t stream) {
    const float* x      = (const float*)d_in[0];
    const int*   ei     = (const int*)  d_in[1];
    const float* attr   = (const float*)d_in[2];
    const float* W_enc  = (const float*)d_in[3];
    const float* b_enc  = (const float*)d_in[4];
    const float* W_gat  = (const float*)d_in[5];
    const float* a_src  = (const float*)d_in[6];
    const float* a_dst  = (const float*)d_in[7];
    const float* Wn1    = (const float*)d_in[8];
    const float* bn1    = (const float*)d_in[9];
    const float* Wn2    = (const float*)d_in[10];
    const float* bn2    = (const float*)d_in[11];
    const float* We1    = (const float*)d_in[12];
    const float* be1    = (const float*)d_in[13];
    const float* We2    = (const float*)d_in[14];
    const float* be2    = (const float*)d_in[15];
    float* out = (float*)d_out;
    float* ws  = (float*)d_ws;

    // workspace layout (float units), total ~58 MB:
    bf16*     hg_psrc = (bf16*)ws;                       // [N*H] bf16: hg, later p_src
    float*    agg     = ws + (size_t)NN * 32;            // [N*H] f32
    bf16*     p_dst   = (bf16*)(ws + (size_t)NN * 96);   // [N*H] bf16
    float*    ssrc    = ws + (size_t)NN * 128;           // [N]
    float*    sdst    = ssrc + NN;                       // [N]
    int*      bcnt    = (int*)(sdst + NN);               // [NBUCK]
    int*      bbase   = bcnt + 512;                      // [NBUCK]
    int*      bcur    = bbase + 512;                     // [NBUCK] start -> end cursor
    unsigned* ebuf    = (unsigned*)(bcur + 512);         // [E] packed (dl<<24 | src)

    const int* srcp = ei;
    const int* dstp = ei + EE;

    hipMemsetAsync(bcnt, 0, NBUCK * sizeof(int), stream);
    k_encode  <<<2048, 256, 0, stream>>>(x, W_enc, b_enc, W_gat, a_src, a_dst,
                                         hg_psrc, ssrc, sdst);
    k_bhist   <<<512, 256, 0, stream>>>(dstp, bcnt);
    k_bscan   <<<1, 512, 0, stream>>>(bcnt, bbase, bcur);
    k_bscatter<<<(EE + 255) / 256, 256, 0, stream>>>(srcp, dstp, bcur, ebuf);
    k_bagg    <<<NBUCK, 512, 0, stream>>>(ebuf, bbase, bcur, ssrc, sdst, hg_psrc, agg);
    k_nodehead<<<2048, 256, 0, stream>>>(agg, Wn1, bn1, Wn2, bn2, We1,
                                         hg_psrc /*p_src*/, p_dst, out);
    k_edgehead<<<8192, 256, 0, stream>>>(srcp, dstp, attr, hg_psrc, p_dst,
                                         We1, be1, We2, be2, out + (size_t)NN * NCLS);
}

// Round 8
// 691.682 us; speedup vs baseline: 2.1157x; 2.1157x over previous
//
#include <hip/hip_runtime.h>
#include <hip/hip_bf16.h>

#define NN   100000
#define EE   1600000
#define DIN  128
#define HH   64
#define DEA  8
#define NCLS 2
#define NPW  4                    // nodes per wave in encode/nodehead
#define BSZ  128                  // dst nodes per bucket
#define NBUCK ((NN + BSZ - 1) / BSZ)   // 782
#define CAP  4096                 // per-bucket LDS edge capacity (mean 2046, sd ~45)

typedef __hip_bfloat16 bf16;

// unpack uint = two packed bf16 (lo = low 16 bits, hi = high 16 bits)
__device__ __forceinline__ void bf2x(unsigned u, float& lo, float& hi) {
    union { unsigned i; float f; } a, b;
    a.i = u << 16; b.i = u & 0xffff0000u;
    lo = a.f; hi = b.f;
}

// ---------- K2: h = relu(x@W_enc+b); hg = h@W_gat (bf16); s_src/s_dst = hg . a ----------
__global__ __launch_bounds__(256) void k_encode(
        const float* __restrict__ x,
        const float* __restrict__ W_enc, const float* __restrict__ b_enc,
        const float* __restrict__ W_gat,
        const float* __restrict__ a_src, const float* __restrict__ a_dst,
        bf16* __restrict__ hg, float* __restrict__ s_src, float* __restrict__ s_dst) {
    __shared__ float wenc[DIN * HH];       // 32 KB
    __shared__ float wgat[HH * HH];        // 16 KB
    __shared__ float hbuf[16][HH];         // 4 KB
    int tid = threadIdx.x;
    for (int i = tid; i < DIN * HH; i += 256) wenc[i] = W_enc[i];
    for (int i = tid; i < HH * HH; i += 256) wgat[i] = W_gat[i];
    int lane = tid & 63;
    int wv = __builtin_amdgcn_readfirstlane(tid >> 6);
    float biasl = b_enc[lane], avsl = a_src[lane], avdl = a_dst[lane];
    __syncthreads();
    for (int base = blockIdx.x * 16; base < NN; base += gridDim.x * 16) {
        int n0 = base + wv * NPW;
        const float* xr = x + (size_t)n0 * DIN;   // wave-uniform
        float h0 = biasl, h1 = biasl, h2 = biasl, h3 = biasl;
        #pragma unroll 4
        for (int d = 0; d < DIN; d++) {
            float w = wenc[d * HH + lane];
            h0 = fmaf(xr[d], w, h0);
            h1 = fmaf(xr[DIN + d], w, h1);
            h2 = fmaf(xr[2 * DIN + d], w, h2);
            h3 = fmaf(xr[3 * DIN + d], w, h3);
        }
        hbuf[wv * NPW + 0][lane] = fmaxf(h0, 0.f);
        hbuf[wv * NPW + 1][lane] = fmaxf(h1, 0.f);
        hbuf[wv * NPW + 2][lane] = fmaxf(h2, 0.f);
        hbuf[wv * NPW + 3][lane] = fmaxf(h3, 0.f);
        __syncthreads();
        float g[NPW] = {0.f, 0.f, 0.f, 0.f};
        #pragma unroll 4
        for (int k = 0; k < HH; k++) {
            float w = wgat[k * HH + lane];
            #pragma unroll
            for (int j = 0; j < NPW; j++) g[j] = fmaf(hbuf[wv * NPW + j][k], w, g[j]);
        }
        #pragma unroll
        for (int j = 0; j < NPW; j++) {
            hg[(size_t)(n0 + j) * HH + lane] = __float2bfloat16(g[j]);
            float ps = g[j] * avsl, pd = g[j] * avdl;
            #pragma unroll
            for (int off = 32; off; off >>= 1) {
                ps += __shfl_xor(ps, off);
                pd += __shfl_xor(pd, off);
            }
            if (lane == 0) { s_src[n0 + j] = ps; s_dst[n0 + j] = pd; }
        }
        __syncthreads();
    }
}

// ---------- B1: bucket histogram (LDS-staged) ----------
__global__ __launch_bounds__(256) void k_bhist(const int* __restrict__ dst,
                                               int* __restrict__ bcnt) {
    __shared__ int h[NBUCK];
    int tid = threadIdx.x;
    for (int i = tid; i < NBUCK; i += 256) h[i] = 0;
    __syncthreads();
    for (int e = blockIdx.x * 256 + tid; e < EE; e += gridDim.x * 256)
        atomicAdd(&h[dst[e] >> 7], 1);            // BSZ = 128
    __syncthreads();
    for (int i = tid; i < NBUCK; i += 256) {
        int v = h[i];
        if (v) atomicAdd(&bcnt[i], v);
    }
}

// ---------- B2: scan bucket counts -> bbase (exclusive), bcur = bbase ----------
__global__ void k_bscan(const int* __restrict__ bcnt,
                        int* __restrict__ bbase, int* __restrict__ bcur) {
    __shared__ int sm[1024];
    int t = threadIdx.x;
    int v = (t < NBUCK) ? bcnt[t] : 0;
    sm[t] = v;
    __syncthreads();
    for (int s = 1; s < 1024; s <<= 1) {
        int add = (t >= s) ? sm[t - s] : 0;
        __syncthreads();
        sm[t] += add;
        __syncthreads();
    }
    if (t < NBUCK) {
        int base = sm[t] - v;
        bbase[t] = base;
        bcur[t]  = base;
    }
}

// ---------- B3: scatter packed (dl<<24 | src) into dense bucket windows ----------
__global__ void k_bscatter(const int* __restrict__ src, const int* __restrict__ dst,
                           int* bcur, unsigned* __restrict__ ebuf) {
    int e = blockIdx.x * blockDim.x + threadIdx.x;
    if (e >= EE) return;
    int dv = dst[e], sv = src[e];
    int b  = dv >> 7;
    int dl = dv & (BSZ - 1);
    int pos = atomicAdd(&bcur[b], 1);
    ebuf[pos] = ((unsigned)dl << 24) | (unsigned)sv;
}

// ---------- B4: per-bucket counting sort in LDS, then wave-per-node register agg ----------
// Block = 512 thr = 8 waves per bucket. Sort: 2 int LDS atomics/edge. Agg: R5's proven
// structure — 8 groups of 8 lanes per wave, lane owns 8 dims (uint4 hg gather),
// single-pass unnormalized softmax (m=0 shift exact: softmax shift-invariant, scores bounded).
__global__ __launch_bounds__(512) void k_bagg2(
        const unsigned* __restrict__ ebuf,
        const int* __restrict__ bbase, const int* __restrict__ bcur,
        const float* __restrict__ s_src, const float* __restrict__ s_dst,
        const bf16* __restrict__ hg, float* __restrict__ agg) {
    __shared__ unsigned sl[CAP];        // 16 KB: src indices in dst-sorted order
    __shared__ int cnt[BSZ];            // per-local-dst degree
    __shared__ int sstart[BSZ];         // local exclusive starts
    __shared__ int spos[BSZ];           // placement cursors
    __shared__ int sscan[BSZ];
    int tid = threadIdx.x;
    int b = blockIdx.x;
    int rs = bbase[b];
    int ne = min(bcur[b] - rs, CAP);
    for (int i = tid; i < BSZ; i += 512) cnt[i] = 0;
    __syncthreads();
    for (int i = tid; i < ne; i += 512)
        atomicAdd(&cnt[ebuf[rs + i] >> 24], 1);
    __syncthreads();
    // exclusive scan of cnt (BSZ=128 elems, Hillis-Steele, whole block syncs)
    int v = (tid < BSZ) ? cnt[tid] : 0;
    if (tid < BSZ) sscan[tid] = v;
    __syncthreads();
    for (int s = 1; s < BSZ; s <<= 1) {
        int add = (tid < BSZ && tid >= s) ? sscan[tid - s] : 0;
        __syncthreads();
        if (tid < BSZ) sscan[tid] += add;
        __syncthreads();
    }
    if (tid < BSZ) { sstart[tid] = sscan[tid] - v; spos[tid] = sscan[tid] - v; }
    __syncthreads();
    // place edges into sorted order
    for (int i = tid; i < ne; i += 512) {
        unsigned p = ebuf[rs + i];
        int dl = p >> 24;
        int q = atomicAdd(&spos[dl], 1);
        sl[q] = p & 0xFFFFFFu;
    }
    __syncthreads();
    // wave-per-node aggregation
    int lane = tid & 63, wv = tid >> 6;
    int lane8 = lane & 7, grp = lane >> 3;
    for (int dl = wv; dl < BSZ; dl += 8) {
        int node = b * BSZ + dl;
        if (node >= NN) break;
        int st = sstart[dl], deg = cnt[dl];
        float sd = s_dst[node];
        float a[8] = {0.f}, denom = 0.f;
        for (int i = grp; i < deg; i += 8) {
            int sv = sl[st + i];
            float s = s_src[sv] + sd;
            s = (s >= 0.f) ? s : 0.2f * s;    // leaky_relu 0.2
            float ex = __expf(s);
            denom += ex;
            uint4 u = *(const uint4*)&hg[(size_t)sv * HH + lane8 * 8];
            float f0, f1, f2, f3, f4, f5, f6, f7;
            bf2x(u.x, f0, f1); bf2x(u.y, f2, f3);
            bf2x(u.z, f4, f5); bf2x(u.w, f6, f7);
            a[0] = fmaf(ex, f0, a[0]); a[1] = fmaf(ex, f1, a[1]);
            a[2] = fmaf(ex, f2, a[2]); a[3] = fmaf(ex, f3, a[3]);
            a[4] = fmaf(ex, f4, a[4]); a[5] = fmaf(ex, f5, a[5]);
            a[6] = fmaf(ex, f6, a[6]); a[7] = fmaf(ex, f7, a[7]);
        }
        #pragma unroll
        for (int off = 8; off < 64; off <<= 1) {
            #pragma unroll
            for (int j = 0; j < 8; j++) a[j] += __shfl_xor(a[j], off);
            denom += __shfl_xor(denom, off);
        }
        if (lane < 8) {
            float inv = 1.f / (denom + 1e-9f);
            float4 r0 = make_float4(a[0] * inv, a[1] * inv, a[2] * inv, a[3] * inv);
            float4 r1 = make_float4(a[4] * inv, a[5] * inv, a[6] * inv, a[7] * inv);
            *(float4*)&agg[(size_t)node * HH + lane8 * 8]     = r0;
            *(float4*)&agg[(size_t)node * HH + lane8 * 8 + 4] = r1;
        }
    }
}

// ---------- K7: xc = relu(agg); node head; bf16 p_src/p_dst partials ----------
// p_src aliases hg (bf16, same indexing; hg dead after k_bagg2). p_dst separate.
__global__ __launch_bounds__(256) void k_nodehead(
        const float* __restrict__ agg,
        const float* __restrict__ Wn1, const float* __restrict__ bn1,
        const float* __restrict__ Wn2, const float* __restrict__ bn2,
        const float* __restrict__ We1,
        bf16* __restrict__ p_src, bf16* __restrict__ p_dst, float* __restrict__ out_node) {
    __shared__ float wn1[HH * HH];     // 16 KB
    __shared__ float we1s[HH * HH];    // 16 KB
    __shared__ float we1d[HH * HH];    // 16 KB
    __shared__ float xbuf[16][HH];     // 4 KB
    int tid = threadIdx.x;
    for (int i = tid; i < HH * HH; i += 256) {
        wn1[i]  = Wn1[i];
        we1s[i] = We1[i];
        we1d[i] = We1[HH * HH + i];
    }
    int lane = tid & 63;
    int wv = __builtin_amdgcn_readfirstlane(tid >> 6);
    float bn1l = bn1[lane];
    float wn2a = Wn2[lane * NCLS + 0], wn2b = Wn2[lane * NCLS + 1];
    float bn20 = bn2[0], bn21 = bn2[1];
    __syncthreads();
    for (int base = blockIdx.x * 16; base < NN; base += gridDim.x * 16) {
        int n0 = base + wv * NPW;
        #pragma unroll
        for (int j = 0; j < NPW; j++)
            xbuf[wv * NPW + j][lane] = fmaxf(agg[(size_t)(n0 + j) * HH + lane], 0.f);
        __syncthreads();
        float tn[NPW], ps[NPW], pd[NPW];
        #pragma unroll
        for (int j = 0; j < NPW; j++) { tn[j] = bn1l; ps[j] = 0.f; pd[j] = 0.f; }
        #pragma unroll 4
        for (int k = 0; k < HH; k++) {
            float w1 = wn1[k * HH + lane];
            float ws = we1s[k * HH + lane];
            float wd = we1d[k * HH + lane];
            #pragma unroll
            for (int j = 0; j < NPW; j++) {
                float xv = xbuf[wv * NPW + j][k];
                tn[j] = fmaf(xv, w1, tn[j]);
                ps[j] = fmaf(xv, ws, ps[j]);
                pd[j] = fmaf(xv, wd, pd[j]);
            }
        }
        #pragma unroll
        for (int j = 0; j < NPW; j++) {
            int node = n0 + j;
            p_src[(size_t)node * HH + lane] = __float2bfloat16(ps[j]);
            p_dst[(size_t)node * HH + lane] = __float2bfloat16(pd[j]);
            float r = fmaxf(tn[j], 0.f);
            float l0 = r * wn2a, l1 = r * wn2b;
            #pragma unroll
            for (int off = 32; off; off >>= 1) {
                l0 += __shfl_xor(l0, off);
                l1 += __shfl_xor(l1, off);
            }
            if (lane == 0)
                *(float2*)&out_node[(size_t)node * NCLS] = make_float2(l0 + bn20, l1 + bn21);
        }
        __syncthreads();
    }
}

// ---------- K8: edge head. 16 lanes per edge-pair (2 edges/group/iter), weights in regs.
__global__ __launch_bounds__(256) void k_edgehead(
        const int* __restrict__ src, const int* __restrict__ dst,
        const float* __restrict__ edge_attr,
        const bf16* __restrict__ p_src, const bf16* __restrict__ p_dst,
        const float* __restrict__ We1, const float* __restrict__ be1,
        const float* __restrict__ We2, const float* __restrict__ be2,
        float* __restrict__ out_edge) {
    int tid = threadIdx.x;
    int lane16 = tid & 15;
    int grp    = (tid & 63) >> 4;
    int wave   = tid >> 6;
    float w1a[DEA][4], w2c0[4], w2c1[4], b1v[4];
    #pragma unroll
    for (int d = 0; d < DEA; d++) {
        float4 v = *(const float4*)&We1[(2 * HH + d) * HH + lane16 * 4];
        w1a[d][0] = v.x; w1a[d][1] = v.y; w1a[d][2] = v.z; w1a[d][3] = v.w;
    }
    float4 bv = *(const float4*)&be1[lane16 * 4];
    b1v[0] = bv.x; b1v[1] = bv.y; b1v[2] = bv.z; b1v[3] = bv.w;
    #pragma unroll
    for (int j = 0; j < 4; j++) {
        w2c0[j] = We2[(lane16 * 4 + j) * NCLS + 0];
        w2c1[j] = We2[(lane16 * 4 + j) * NCLS + 1];
    }
    float be20 = be2[0], be21 = be2[1];

    int stride = gridDim.x * 32;   // 32 edges per block-iteration
    for (int e = blockIdx.x * 32 + wave * 8 + grp * 2; e < EE; e += stride) {
        int ea = e, eb = e + 1;
        int sva = src[ea], dva = dst[ea];
        int svb = src[eb], dvb = dst[eb];
        uint2 usa = *(const uint2*)&p_src[(size_t)sva * HH + lane16 * 4];
        uint2 uda = *(const uint2*)&p_dst[(size_t)dva * HH + lane16 * 4];
        uint2 usb = *(const uint2*)&p_src[(size_t)svb * HH + lane16 * 4];
        uint2 udb = *(const uint2*)&p_dst[(size_t)dvb * HH + lane16 * 4];
        float4 aa0 = *(const float4*)&edge_attr[(size_t)ea * DEA];
        float4 aa1 = *(const float4*)&edge_attr[(size_t)ea * DEA + 4];
        float4 ab0 = *(const float4*)&edge_attr[(size_t)eb * DEA];
        float4 ab1 = *(const float4*)&edge_attr[(size_t)eb * DEA + 4];
        float ava[DEA] = {aa0.x, aa0.y, aa0.z, aa0.w, aa1.x, aa1.y, aa1.z, aa1.w};
        float avb[DEA] = {ab0.x, ab0.y, ab0.z, ab0.w, ab1.x, ab1.y, ab1.z, ab1.w};
        float sa0, sa1, sa2, sa3, da0, da1, da2, da3;
        float sb0, sb1, sb2, sb3, db0, db1, db2, db3;
        bf2x(usa.x, sa0, sa1); bf2x(usa.y, sa2, sa3);
        bf2x(uda.x, da0, da1); bf2x(uda.y, da2, da3);
        bf2x(usb.x, sb0, sb1); bf2x(usb.y, sb2, sb3);
        bf2x(udb.x, db0, db1); bf2x(udb.y, db2, db3);
        float ta[4] = {sa0 + da0 + b1v[0], sa1 + da1 + b1v[1],
                       sa2 + da2 + b1v[2], sa3 + da3 + b1v[3]};
        float tb[4] = {sb0 + db0 + b1v[0], sb1 + db1 + b1v[1],
                       sb2 + db2 + b1v[2], sb3 + db3 + b1v[3]};
        float l0a = 0.f, l1a = 0.f, l0b = 0.f, l1b = 0.f;
        #pragma unroll
        for (int j = 0; j < 4; j++) {
            #pragma unroll
            for (int d = 0; d < DEA; d++) {
                ta[j] = fmaf(ava[d], w1a[d][j], ta[j]);
                tb[j] = fmaf(avb[d], w1a[d][j], tb[j]);
            }
            float ra = fmaxf(ta[j], 0.f), rb = fmaxf(tb[j], 0.f);
            l0a = fmaf(ra, w2c0[j], l0a); l1a = fmaf(ra, w2c1[j], l1a);
            l0b = fmaf(rb, w2c0[j], l0b); l1b = fmaf(rb, w2c1[j], l1b);
        }
        #pragma unroll
        for (int off = 8; off; off >>= 1) {
            l0a += __shfl_xor(l0a, off); l1a += __shfl_xor(l1a, off);
            l0b += __shfl_xor(l0b, off); l1b += __shfl_xor(l1b, off);
        }
        if (lane16 == 0) {
            *(float2*)&out_edge[(size_t)ea * NCLS] = make_float2(l0a + be20, l1a + be21);
            *(float2*)&out_edge[(size_t)eb * NCLS] = make_float2(l0b + be20, l1b + be21);
        }
    }
}

extern "C" void kernel_launch(void* const* d_in, const int* in_sizes, int n_in,
                              void* d_out, int out_size, void* d_ws, size_t ws_size,
                              hipStream_t stream) {
    const float* x      = (const float*)d_in[0];
    const int*   ei     = (const int*)  d_in[1];
    const float* attr   = (const float*)d_in[2];
    const float* W_enc  = (const float*)d_in[3];
    const float* b_enc  = (const float*)d_in[4];
    const float* W_gat  = (const float*)d_in[5];
    const float* a_src  = (const float*)d_in[6];
    const float* a_dst  = (const float*)d_in[7];
    const float* Wn1    = (const float*)d_in[8];
    const float* bn1    = (const float*)d_in[9];
    const float* Wn2    = (const float*)d_in[10];
    const float* bn2    = (const float*)d_in[11];
    const float* We1    = (const float*)d_in[12];
    const float* be1    = (const float*)d_in[13];
    const float* We2    = (const float*)d_in[14];
    const float* be2    = (const float*)d_in[15];
    float* out = (float*)d_out;
    float* ws  = (float*)d_ws;

    // workspace layout (float units), total ~58 MB:
    bf16*     hg_psrc = (bf16*)ws;                       // [N*H] bf16: hg, later p_src
    float*    agg     = ws + (size_t)NN * 32;            // [N*H] f32
    bf16*     p_dst   = (bf16*)(ws + (size_t)NN * 96);   // [N*H] bf16
    float*    ssrc    = ws + (size_t)NN * 128;           // [N]
    float*    sdst    = ssrc + NN;                       // [N]
    int*      bcnt    = (int*)(sdst + NN);               // [NBUCK]
    int*      bbase   = bcnt + 1024;                     // [NBUCK]
    int*      bcur    = bbase + 1024;                    // [NBUCK] start -> end cursor
    unsigned* ebuf    = (unsigned*)(bcur + 1024);        // [E] packed (dl<<24 | src)

    const int* srcp = ei;
    const int* dstp = ei + EE;

    hipMemsetAsync(bcnt, 0, NBUCK * sizeof(int), stream);
    k_encode  <<<2048, 256, 0, stream>>>(x, W_enc, b_enc, W_gat, a_src, a_dst,
                                         hg_psrc, ssrc, sdst);
    k_bhist   <<<512, 256, 0, stream>>>(dstp, bcnt);
    k_bscan   <<<1, 1024, 0, stream>>>(bcnt, bbase, bcur);
    k_bscatter<<<(EE + 255) / 256, 256, 0, stream>>>(srcp, dstp, bcur, ebuf);
    k_bagg2   <<<NBUCK, 512, 0, stream>>>(ebuf, bbase, bcur, ssrc, sdst, hg_psrc, agg);
    k_nodehead<<<2048, 256, 0, stream>>>(agg, Wn1, bn1, Wn2, bn2, We1,
                                         hg_psrc /*p_src*/, p_dst, out);
    k_edgehead<<<8192, 256, 0, stream>>>(srcp, dstp, attr, hg_psrc, p_dst,
                                         We1, be1, We2, be2, out + (size_t)NN * NCLS);
}

// Round 9
// 333.954 us; speedup vs baseline: 4.3820x; 2.0712x over previous
//
#include <hip/hip_runtime.h>
#include <hip/hip_bf16.h>

#define NN   100000
#define EE   1600000
#define DIN  128
#define HH   64
#define DEA  8
#define NCLS 2
#define NPW  4                    // nodes per wave in encode/nodehead
#define BSZ  128                  // dst nodes per bucket
#define NBUCK ((NN + BSZ - 1) / BSZ)   // 782
#define CAPG 2368                 // per-bucket window capacity (mean 2046, sd ~45, +7 sigma)
#define CAP  4096                 // per-bucket LDS edge capacity in k_bagg2
#define NCHUNK 100                // scatter blocks; EE/NCHUNK = 16000 edges each, exact
#define CHUNK (EE / NCHUNK)

typedef __hip_bfloat16 bf16;

// unpack uint = two packed bf16 (lo = low 16 bits, hi = high 16 bits)
__device__ __forceinline__ void bf2x(unsigned u, float& lo, float& hi) {
    union { unsigned i; float f; } a, b;
    a.i = u << 16; b.i = u & 0xffff0000u;
    lo = a.f; hi = b.f;
}

// ---------- K2: h = relu(x@W_enc+b); hg = h@W_gat (bf16); s_src/s_dst = hg . a ----------
__global__ __launch_bounds__(256) void k_encode(
        const float* __restrict__ x,
        const float* __restrict__ W_enc, const float* __restrict__ b_enc,
        const float* __restrict__ W_gat,
        const float* __restrict__ a_src, const float* __restrict__ a_dst,
        bf16* __restrict__ hg, float* __restrict__ s_src, float* __restrict__ s_dst) {
    __shared__ float wenc[DIN * HH];       // 32 KB
    __shared__ float wgat[HH * HH];        // 16 KB
    __shared__ float hbuf[16][HH];         // 4 KB
    int tid = threadIdx.x;
    for (int i = tid; i < DIN * HH; i += 256) wenc[i] = W_enc[i];
    for (int i = tid; i < HH * HH; i += 256) wgat[i] = W_gat[i];
    int lane = tid & 63;
    int wv = __builtin_amdgcn_readfirstlane(tid >> 6);
    float biasl = b_enc[lane], avsl = a_src[lane], avdl = a_dst[lane];
    __syncthreads();
    for (int base = blockIdx.x * 16; base < NN; base += gridDim.x * 16) {
        int n0 = base + wv * NPW;
        const float* xr = x + (size_t)n0 * DIN;   // wave-uniform
        float h0 = biasl, h1 = biasl, h2 = biasl, h3 = biasl;
        #pragma unroll 4
        for (int d = 0; d < DIN; d++) {
            float w = wenc[d * HH + lane];
            h0 = fmaf(xr[d], w, h0);
            h1 = fmaf(xr[DIN + d], w, h1);
            h2 = fmaf(xr[2 * DIN + d], w, h2);
            h3 = fmaf(xr[3 * DIN + d], w, h3);
        }
        hbuf[wv * NPW + 0][lane] = fmaxf(h0, 0.f);
        hbuf[wv * NPW + 1][lane] = fmaxf(h1, 0.f);
        hbuf[wv * NPW + 2][lane] = fmaxf(h2, 0.f);
        hbuf[wv * NPW + 3][lane] = fmaxf(h3, 0.f);
        __syncthreads();
        float g[NPW] = {0.f, 0.f, 0.f, 0.f};
        #pragma unroll 4
        for (int k = 0; k < HH; k++) {
            float w = wgat[k * HH + lane];
            #pragma unroll
            for (int j = 0; j < NPW; j++) g[j] = fmaf(hbuf[wv * NPW + j][k], w, g[j]);
        }
        #pragma unroll
        for (int j = 0; j < NPW; j++) {
            hg[(size_t)(n0 + j) * HH + lane] = __float2bfloat16(g[j]);
            float ps = g[j] * avsl, pd = g[j] * avdl;
            #pragma unroll
            for (int off = 32; off; off >>= 1) {
                ps += __shfl_xor(ps, off);
                pd += __shfl_xor(pd, off);
            }
            if (lane == 0) { s_src[n0 + j] = ps; s_dst[n0 + j] = pd; }
        }
        __syncthreads();
    }
}

// ---------- B3': two-level scatter. Block owns CHUNK=16000 edges.
// Pass 1: LDS histogram. Reserve: 1 global fetch-add per (block,bucket) -> atomic depth
// per address = NCHUNK (was 2046 in R8's per-edge version). Pass 2: LDS cursors place
// edges into fixed-capacity windows ebuf[b*CAPG ...]. bcur[b] ends as bucket count.
__global__ __launch_bounds__(256) void k_cscatter(
        const int* __restrict__ src, const int* __restrict__ dst,
        int* bcur, unsigned* __restrict__ ebuf) {
    __shared__ int cnt[NBUCK];
    __shared__ int cur[NBUCK];
    int tid = threadIdx.x;
    int e0 = blockIdx.x * CHUNK;
    for (int i = tid; i < NBUCK; i += 256) cnt[i] = 0;
    __syncthreads();
    for (int i = tid; i < CHUNK; i += 256)
        atomicAdd(&cnt[dst[e0 + i] >> 7], 1);          // BSZ = 128
    __syncthreads();
    for (int i = tid; i < NBUCK; i += 256) {
        int c = cnt[i];
        int base = c ? atomicAdd(&bcur[i], c) : 0;     // reserve range in bucket window
        cur[i] = i * CAPG + base;
    }
    __syncthreads();
    for (int i = tid; i < CHUNK; i += 256) {
        int dv = dst[e0 + i], sv = src[e0 + i];
        int b  = dv >> 7;
        int dl = dv & (BSZ - 1);
        int pos = atomicAdd(&cur[b], 1);
        ebuf[pos] = ((unsigned)dl << 24) | (unsigned)sv;
    }
}

// ---------- B4: per-bucket counting sort in LDS, then wave-per-node register agg ----------
// Block = 512 thr = 8 waves per bucket. Sort: 2 int LDS atomics/edge. Agg: 8 groups of
// 8 lanes per wave, lane owns 8 dims (uint4 hg gather), single-pass unnormalized softmax
// (m=0 shift exact: softmax shift-invariant, scores bounded).
__global__ __launch_bounds__(512) void k_bagg2(
        const unsigned* __restrict__ ebuf, const int* __restrict__ bcur,
        const float* __restrict__ s_src, const float* __restrict__ s_dst,
        const bf16* __restrict__ hg, float* __restrict__ agg) {
    __shared__ unsigned sl[CAP];        // 16 KB: src indices in dst-sorted order
    __shared__ int cnt[BSZ];            // per-local-dst degree
    __shared__ int sstart[BSZ];         // local exclusive starts
    __shared__ int spos[BSZ];           // placement cursors
    __shared__ int sscan[BSZ];
    int tid = threadIdx.x;
    int b = blockIdx.x;
    int rs = b * CAPG;
    int ne = min(bcur[b], CAP);
    for (int i = tid; i < BSZ; i += 512) cnt[i] = 0;
    __syncthreads();
    for (int i = tid; i < ne; i += 512)
        atomicAdd(&cnt[ebuf[rs + i] >> 24], 1);
    __syncthreads();
    // exclusive scan of cnt (BSZ=128 elems, Hillis-Steele, whole block syncs)
    int v = (tid < BSZ) ? cnt[tid] : 0;
    if (tid < BSZ) sscan[tid] = v;
    __syncthreads();
    for (int s = 1; s < BSZ; s <<= 1) {
        int add = (tid < BSZ && tid >= s) ? sscan[tid - s] : 0;
        __syncthreads();
        if (tid < BSZ) sscan[tid] += add;
        __syncthreads();
    }
    if (tid < BSZ) { sstart[tid] = sscan[tid] - v; spos[tid] = sscan[tid] - v; }
    __syncthreads();
    // place edges into sorted order
    for (int i = tid; i < ne; i += 512) {
        unsigned p = ebuf[rs + i];
        int dl = p >> 24;
        int q = atomicAdd(&spos[dl], 1);
        sl[q] = p & 0xFFFFFFu;
    }
    __syncthreads();
    // wave-per-node aggregation
    int lane = tid & 63, wv = tid >> 6;
    int lane8 = lane & 7, grp = lane >> 3;
    for (int dl = wv; dl < BSZ; dl += 8) {
        int node = b * BSZ + dl;
        if (node >= NN) break;
        int st = sstart[dl], deg = cnt[dl];
        float sd = s_dst[node];
        float a[8] = {0.f}, denom = 0.f;
        for (int i = grp; i < deg; i += 8) {
            int sv = sl[st + i];
            float s = s_src[sv] + sd;
            s = (s >= 0.f) ? s : 0.2f * s;    // leaky_relu 0.2
            float ex = __expf(s);
            denom += ex;
            uint4 u = *(const uint4*)&hg[(size_t)sv * HH + lane8 * 8];
            float f0, f1, f2, f3, f4, f5, f6, f7;
            bf2x(u.x, f0, f1); bf2x(u.y, f2, f3);
            bf2x(u.z, f4, f5); bf2x(u.w, f6, f7);
            a[0] = fmaf(ex, f0, a[0]); a[1] = fmaf(ex, f1, a[1]);
            a[2] = fmaf(ex, f2, a[2]); a[3] = fmaf(ex, f3, a[3]);
            a[4] = fmaf(ex, f4, a[4]); a[5] = fmaf(ex, f5, a[5]);
            a[6] = fmaf(ex, f6, a[6]); a[7] = fmaf(ex, f7, a[7]);
        }
        #pragma unroll
        for (int off = 8; off < 64; off <<= 1) {
            #pragma unroll
            for (int j = 0; j < 8; j++) a[j] += __shfl_xor(a[j], off);
            denom += __shfl_xor(denom, off);
        }
        if (lane < 8) {
            float inv = 1.f / (denom + 1e-9f);
            float4 r0 = make_float4(a[0] * inv, a[1] * inv, a[2] * inv, a[3] * inv);
            float4 r1 = make_float4(a[4] * inv, a[5] * inv, a[6] * inv, a[7] * inv);
            *(float4*)&agg[(size_t)node * HH + lane8 * 8]     = r0;
            *(float4*)&agg[(size_t)node * HH + lane8 * 8 + 4] = r1;
        }
    }
}

// ---------- K7: xc = relu(agg); node head; bf16 p_src/p_dst partials ----------
// p_src aliases hg (bf16, same indexing; hg dead after k_bagg2). p_dst separate.
__global__ __launch_bounds__(256) void k_nodehead(
        const float* __restrict__ agg,
        const float* __restrict__ Wn1, const float* __restrict__ bn1,
        const float* __restrict__ Wn2, const float* __restrict__ bn2,
        const float* __restrict__ We1,
        bf16* __restrict__ p_src, bf16* __restrict__ p_dst, float* __restrict__ out_node) {
    __shared__ float wn1[HH * HH];     // 16 KB
    __shared__ float we1s[HH * HH];    // 16 KB
    __shared__ float we1d[HH * HH];    // 16 KB
    __shared__ float xbuf[16][HH];     // 4 KB
    int tid = threadIdx.x;
    for (int i = tid; i < HH * HH; i += 256) {
        wn1[i]  = Wn1[i];
        we1s[i] = We1[i];
        we1d[i] = We1[HH * HH + i];
    }
    int lane = tid & 63;
    int wv = __builtin_amdgcn_readfirstlane(tid >> 6);
    float bn1l = bn1[lane];
    float wn2a = Wn2[lane * NCLS + 0], wn2b = Wn2[lane * NCLS + 1];
    float bn20 = bn2[0], bn21 = bn2[1];
    __syncthreads();
    for (int base = blockIdx.x * 16; base < NN; base += gridDim.x * 16) {
        int n0 = base + wv * NPW;
        #pragma unroll
        for (int j = 0; j < NPW; j++)
            xbuf[wv * NPW + j][lane] = fmaxf(agg[(size_t)(n0 + j) * HH + lane], 0.f);
        __syncthreads();
        float tn[NPW], ps[NPW], pd[NPW];
        #pragma unroll
        for (int j = 0; j < NPW; j++) { tn[j] = bn1l; ps[j] = 0.f; pd[j] = 0.f; }
        #pragma unroll 4
        for (int k = 0; k < HH; k++) {
            float w1 = wn1[k * HH + lane];
            float ws = we1s[k * HH + lane];
            float wd = we1d[k * HH + lane];
            #pragma unroll
            for (int j = 0; j < NPW; j++) {
                float xv = xbuf[wv * NPW + j][k];
                tn[j] = fmaf(xv, w1, tn[j]);
                ps[j] = fmaf(xv, ws, ps[j]);
                pd[j] = fmaf(xv, wd, pd[j]);
            }
        }
        #pragma unroll
        for (int j = 0; j < NPW; j++) {
            int node = n0 + j;
            p_src[(size_t)node * HH + lane] = __float2bfloat16(ps[j]);
            p_dst[(size_t)node * HH + lane] = __float2bfloat16(pd[j]);
            float r = fmaxf(tn[j], 0.f);
            float l0 = r * wn2a, l1 = r * wn2b;
            #pragma unroll
            for (int off = 32; off; off >>= 1) {
                l0 += __shfl_xor(l0, off);
                l1 += __shfl_xor(l1, off);
            }
            if (lane == 0)
                *(float2*)&out_node[(size_t)node * NCLS] = make_float2(l0 + bn20, l1 + bn21);
        }
        __syncthreads();
    }
}

// ---------- K8: edge head. 16 lanes per edge-pair (2 edges/group/iter), weights in regs.
__global__ __launch_bounds__(256) void k_edgehead(
        const int* __restrict__ src, const int* __restrict__ dst,
        const float* __restrict__ edge_attr,
        const bf16* __restrict__ p_src, const bf16* __restrict__ p_dst,
        const float* __restrict__ We1, const float* __restrict__ be1,
        const float* __restrict__ We2, const float* __restrict__ be2,
        float* __restrict__ out_edge) {
    int tid = threadIdx.x;
    int lane16 = tid & 15;
    int grp    = (tid & 63) >> 4;
    int wave   = tid >> 6;
    float w1a[DEA][4], w2c0[4], w2c1[4], b1v[4];
    #pragma unroll
    for (int d = 0; d < DEA; d++) {
        float4 v = *(const float4*)&We1[(2 * HH + d) * HH + lane16 * 4];
        w1a[d][0] = v.x; w1a[d][1] = v.y; w1a[d][2] = v.z; w1a[d][3] = v.w;
    }
    float4 bv = *(const float4*)&be1[lane16 * 4];
    b1v[0] = bv.x; b1v[1] = bv.y; b1v[2] = bv.z; b1v[3] = bv.w;
    #pragma unroll
    for (int j = 0; j < 4; j++) {
        w2c0[j] = We2[(lane16 * 4 + j) * NCLS + 0];
        w2c1[j] = We2[(lane16 * 4 + j) * NCLS + 1];
    }
    float be20 = be2[0], be21 = be2[1];

    int stride = gridDim.x * 32;   // 32 edges per block-iteration
    for (int e = blockIdx.x * 32 + wave * 8 + grp * 2; e < EE; e += stride) {
        int ea = e, eb = e + 1;
        int sva = src[ea], dva = dst[ea];
        int svb = src[eb], dvb = dst[eb];
        uint2 usa = *(const uint2*)&p_src[(size_t)sva * HH + lane16 * 4];
        uint2 uda = *(const uint2*)&p_dst[(size_t)dva * HH + lane16 * 4];
        uint2 usb = *(const uint2*)&p_src[(size_t)svb * HH + lane16 * 4];
        uint2 udb = *(const uint2*)&p_dst[(size_t)dvb * HH + lane16 * 4];
        float4 aa0 = *(const float4*)&edge_attr[(size_t)ea * DEA];
        float4 aa1 = *(const float4*)&edge_attr[(size_t)ea * DEA + 4];
        float4 ab0 = *(const float4*)&edge_attr[(size_t)eb * DEA];
        float4 ab1 = *(const float4*)&edge_attr[(size_t)eb * DEA + 4];
        float ava[DEA] = {aa0.x, aa0.y, aa0.z, aa0.w, aa1.x, aa1.y, aa1.z, aa1.w};
        float avb[DEA] = {ab0.x, ab0.y, ab0.z, ab0.w, ab1.x, ab1.y, ab1.z, ab1.w};
        float sa0, sa1, sa2, sa3, da0, da1, da2, da3;
        float sb0, sb1, sb2, sb3, db0, db1, db2, db3;
        bf2x(usa.x, sa0, sa1); bf2x(usa.y, sa2, sa3);
        bf2x(uda.x, da0, da1); bf2x(uda.y, da2, da3);
        bf2x(usb.x, sb0, sb1); bf2x(usb.y, sb2, sb3);
        bf2x(udb.x, db0, db1); bf2x(udb.y, db2, db3);
        float ta[4] = {sa0 + da0 + b1v[0], sa1 + da1 + b1v[1],
                       sa2 + da2 + b1v[2], sa3 + da3 + b1v[3]};
        float tb[4] = {sb0 + db0 + b1v[0], sb1 + db1 + b1v[1],
                       sb2 + db2 + b1v[2], sb3 + db3 + b1v[3]};
        float l0a = 0.f, l1a = 0.f, l0b = 0.f, l1b = 0.f;
        #pragma unroll
        for (int j = 0; j < 4; j++) {
            #pragma unroll
            for (int d = 0; d < DEA; d++) {
                ta[j] = fmaf(ava[d], w1a[d][j], ta[j]);
                tb[j] = fmaf(avb[d], w1a[d][j], tb[j]);
            }
            float ra = fmaxf(ta[j], 0.f), rb = fmaxf(tb[j], 0.f);
            l0a = fmaf(ra, w2c0[j], l0a); l1a = fmaf(ra, w2c1[j], l1a);
            l0b = fmaf(rb, w2c0[j], l0b); l1b = fmaf(rb, w2c1[j], l1b);
        }
        #pragma unroll
        for (int off = 8; off; off >>= 1) {
            l0a += __shfl_xor(l0a, off); l1a += __shfl_xor(l1a, off);
            l0b += __shfl_xor(l0b, off); l1b += __shfl_xor(l1b, off);
        }
        if (lane16 == 0) {
            *(float2*)&out_edge[(size_t)ea * NCLS] = make_float2(l0a + be20, l1a + be21);
            *(float2*)&out_edge[(size_t)eb * NCLS] = make_float2(l0b + be20, l1b + be21);
        }
    }
}

extern "C" void kernel_launch(void* const* d_in, const int* in_sizes, int n_in,
                              void* d_out, int out_size, void* d_ws, size_t ws_size,
                              hipStream_t stream) {
    const float* x      = (const float*)d_in[0];
    const int*   ei     = (const int*)  d_in[1];
    const float* attr   = (const float*)d_in[2];
    const float* W_enc  = (const float*)d_in[3];
    const float* b_enc  = (const float*)d_in[4];
    const float* W_gat  = (const float*)d_in[5];
    const float* a_src  = (const float*)d_in[6];
    const float* a_dst  = (const float*)d_in[7];
    const float* Wn1    = (const float*)d_in[8];
    const float* bn1    = (const float*)d_in[9];
    const float* Wn2    = (const float*)d_in[10];
    const float* bn2    = (const float*)d_in[11];
    const float* We1    = (const float*)d_in[12];
    const float* be1    = (const float*)d_in[13];
    const float* We2    = (const float*)d_in[14];
    const float* be2    = (const float*)d_in[15];
    float* out = (float*)d_out;
    float* ws  = (float*)d_ws;

    // workspace layout (float units), total ~60 MB:
    bf16*     hg_psrc = (bf16*)ws;                       // [N*H] bf16: hg, later p_src
    float*    agg     = ws + (size_t)NN * 32;            // [N*H] f32
    bf16*     p_dst   = (bf16*)(ws + (size_t)NN * 96);   // [N*H] bf16
    float*    ssrc    = ws + (size_t)NN * 128;           // [N]
    float*    sdst    = ssrc + NN;                       // [N]
    int*      bcur    = (int*)(sdst + NN);               // [NBUCK] count cursors
    unsigned* ebuf    = (unsigned*)(bcur + 1024);        // [NBUCK*CAPG] bucket windows

    const int* srcp = ei;
    const int* dstp = ei + EE;

    hipMemsetAsync(bcur, 0, NBUCK * sizeof(int), stream);
    k_encode  <<<2048, 256, 0, stream>>>(x, W_enc, b_enc, W_gat, a_src, a_dst,
                                         hg_psrc, ssrc, sdst);
    k_cscatter<<<NCHUNK, 256, 0, stream>>>(srcp, dstp, bcur, ebuf);
    k_bagg2   <<<NBUCK, 512, 0, stream>>>(ebuf, bcur, ssrc, sdst, hg_psrc, agg);
    k_nodehead<<<2048, 256, 0, stream>>>(agg, Wn1, bn1, Wn2, bn2, We1,
                                         hg_psrc /*p_src*/, p_dst, out);
    k_edgehead<<<8192, 256, 0, stream>>>(srcp, dstp, attr, hg_psrc, p_dst,
                                         We1, be1, We2, be2, out + (size_t)NN * NCLS);
}

// Round 10
// 268.503 us; speedup vs baseline: 5.4501x; 1.2438x over previous
//
#include <hip/hip_runtime.h>
#include <hip/hip_bf16.h>

#define NN   100000
#define EE   1600000
#define DIN  128
#define HH   64
#define DEA  8
#define NCLS 2
#define NPW  4                    // nodes per wave in nodehead
#define BSZ  128                  // dst nodes per bucket
#define NBUCK ((NN + BSZ - 1) / BSZ)   // 782
#define CAPG 2368                 // per-bucket window capacity (mean 2046, sd ~45, +7 sigma)
#define CAP  4096                 // per-bucket LDS edge capacity in k_bagg2
#define NCHUNK 100                // scatter blocks; EE/NCHUNK = 16000 edges each, exact
#define CHUNK (EE / NCHUNK)

typedef __hip_bfloat16 bf16;
typedef short  short8 __attribute__((ext_vector_type(8)));
typedef float  f32x4  __attribute__((ext_vector_type(4)));

// unpack uint = two packed bf16 (lo = low 16 bits, hi = high 16 bits)
__device__ __forceinline__ void bf2x(unsigned u, float& lo, float& hi) {
    union { unsigned i; float f; } a, b;
    a.i = u << 16; b.i = u & 0xffff0000u;
    lo = a.f; hi = b.f;
}
// f32 -> bf16 bits, round-to-nearest-even
__device__ __forceinline__ short f2bs(float f) {
    unsigned u = __float_as_uint(f);
    return (short)((u + 0x7fffu + ((u >> 16) & 1u)) >> 16);
}
__device__ __forceinline__ short8 cvt8(float4 a, float4 b) {
    short8 r;
    r[0] = f2bs(a.x); r[1] = f2bs(a.y); r[2] = f2bs(a.z); r[3] = f2bs(a.w);
    r[4] = f2bs(b.x); r[5] = f2bs(b.y); r[6] = f2bs(b.z); r[7] = f2bs(b.w);
    return r;
}
__device__ __forceinline__ f32x4 z4() {
    f32x4 z; z[0] = 0.f; z[1] = 0.f; z[2] = 0.f; z[3] = 0.f; return z;
}

// ---------- K2 (MFMA): h = relu(x@W_enc+b); hg = h@W_gat; s_src/s_dst = hg . a ----------
// mfma_f32_16x16x32_bf16. A-frag: row=lane&15, k=(lane>>4)*8+i. B-frag: col=lane&15,
// k=(lane>>4)*8+i. D: row=(lane>>4)*4+r, col=lane&15 (m89-verified). Wave owns 2x16 rows;
// weights staged transposed bf16 in LDS (+pad), W_gat frags hoisted to registers; per-wave
// f32 transpose buffer between GEMMs (wave-local LDS => in-order, no barrier needed).
#define WE_STRIDE 136
#define WG_STRIDE 72
#define TB_STRIDE 68
__global__ __launch_bounds__(256) void k_encode(
        const float* __restrict__ x,
        const float* __restrict__ W_enc, const float* __restrict__ b_enc,
        const float* __restrict__ W_gat,
        const float* __restrict__ a_src, const float* __restrict__ a_dst,
        bf16* __restrict__ hg_, float* __restrict__ s_src, float* __restrict__ s_dst) {
    __shared__ short wencT[64 * WE_STRIDE];   // [n][k] bf16, 17408 B
    __shared__ short wgatT[64 * WG_STRIDE];   // [n][k] bf16,  9216 B
    __shared__ float tb[4][16 * TB_STRIDE];   // per-wave transpose buf, 17408 B
    short* hg = (short*)hg_;
    int tid = threadIdx.x;
    for (int i = tid; i < DIN * HH; i += 256) {          // coalesced read, scattered LDS write
        int k = i >> 6, n = i & 63;
        wencT[n * WE_STRIDE + k] = f2bs(W_enc[i]);
    }
    for (int i = tid; i < HH * HH; i += 256) {
        int k = i >> 6, n = i & 63;
        wgatT[n * WG_STRIDE + k] = f2bs(W_gat[i]);
    }
    __syncthreads();
    int w = tid >> 6, l = tid & 63, m = l & 15, h = l >> 4;
    short8 wg[2][4];                                     // hoisted W_gat B-frags
    #pragma unroll
    for (int kt = 0; kt < 2; kt++)
        #pragma unroll
        for (int nt = 0; nt < 4; nt++)
            wg[kt][nt] = *(short8*)&wgatT[(nt * 16 + m) * WG_STRIDE + kt * 32 + h * 8];
    float avs[4], avd[4], ben[4];
    #pragma unroll
    for (int nt = 0; nt < 4; nt++) {
        avs[nt] = a_src[nt * 16 + m];
        avd[nt] = a_dst[nt * 16 + m];
        ben[nt] = b_enc[nt * 16 + m];
    }
    int tp = blockIdx.x * 4 + w;                         // tile-pair id, 32 rows each
    if (tp >= NN / 32) return;                           // 3125 exact; after the only barrier
    int n0 = tp * 32;
    float* tbw = tb[w];

    f32x4 acc1[2][4];
    #pragma unroll
    for (int rt = 0; rt < 2; rt++)
        #pragma unroll
        for (int nt = 0; nt < 4; nt++) acc1[rt][nt] = z4();
    #pragma unroll
    for (int kt = 0; kt < 4; kt++) {
        short8 af[2];
        #pragma unroll
        for (int rt = 0; rt < 2; rt++) {
            const float* xp = &x[(size_t)(n0 + rt * 16 + m) * DIN + kt * 32 + h * 8];
            af[rt] = cvt8(*(const float4*)xp, *(const float4*)(xp + 4));
        }
        #pragma unroll
        for (int nt = 0; nt < 4; nt++) {
            short8 bf = *(short8*)&wencT[(nt * 16 + m) * WE_STRIDE + kt * 32 + h * 8];
            acc1[0][nt] = __builtin_amdgcn_mfma_f32_16x16x32_bf16(af[0], bf, acc1[0][nt], 0, 0, 0);
            acc1[1][nt] = __builtin_amdgcn_mfma_f32_16x16x32_bf16(af[1], bf, acc1[1][nt], 0, 0, 0);
        }
    }
    #pragma unroll
    for (int rt = 0; rt < 2; rt++) {
        #pragma unroll
        for (int nt = 0; nt < 4; nt++)
            #pragma unroll
            for (int r = 0; r < 4; r++) {
                float hv = fmaxf(acc1[rt][nt][r] + ben[nt], 0.f);
                tbw[(h * 4 + r) * TB_STRIDE + nt * 16 + m] = hv;   // h-tile, [row][dim]
            }
        f32x4 acc2[4];
        #pragma unroll
        for (int nt = 0; nt < 4; nt++) acc2[nt] = z4();
        #pragma unroll
        for (int kt = 0; kt < 2; kt++) {
            const float* tp_ = &tbw[m * TB_STRIDE + kt * 32 + h * 8];
            short8 af2 = cvt8(*(const float4*)tp_, *(const float4*)(tp_ + 4));
            #pragma unroll
            for (int nt = 0; nt < 4; nt++)
                acc2[nt] = __builtin_amdgcn_mfma_f32_16x16x32_bf16(af2, wg[kt][nt], acc2[nt], 0, 0, 0);
        }
        float ps[4] = {0.f, 0.f, 0.f, 0.f}, pd[4] = {0.f, 0.f, 0.f, 0.f};
        #pragma unroll
        for (int nt = 0; nt < 4; nt++)
            #pragma unroll
            for (int r = 0; r < 4; r++) {
                float v = acc2[nt][r];
                ps[r] = fmaf(v, avs[nt], ps[r]);
                pd[r] = fmaf(v, avd[nt], pd[r]);
                hg[(size_t)(n0 + rt * 16 + h * 4 + r) * HH + nt * 16 + m] = f2bs(v);
            }
        #pragma unroll
        for (int off = 1; off < 16; off <<= 1)
            #pragma unroll
            for (int r = 0; r < 4; r++) {
                ps[r] += __shfl_xor(ps[r], off);
                pd[r] += __shfl_xor(pd[r], off);
            }
        if (m == 0) {
            *(float4*)&s_src[n0 + rt * 16 + h * 4] = make_float4(ps[0], ps[1], ps[2], ps[3]);
            *(float4*)&s_dst[n0 + rt * 16 + h * 4] = make_float4(pd[0], pd[1], pd[2], pd[3]);
        }
    }
}

// ---------- B3': two-level scatter. Block owns CHUNK=16000 edges. ----------
__global__ __launch_bounds__(256) void k_cscatter(
        const int* __restrict__ src, const int* __restrict__ dst,
        int* bcur, unsigned* __restrict__ ebuf) {
    __shared__ int cnt[NBUCK];
    __shared__ int cur[NBUCK];
    int tid = threadIdx.x;
    int e0 = blockIdx.x * CHUNK;
    for (int i = tid; i < NBUCK; i += 256) cnt[i] = 0;
    __syncthreads();
    for (int i = tid; i < CHUNK; i += 256)
        atomicAdd(&cnt[dst[e0 + i] >> 7], 1);          // BSZ = 128
    __syncthreads();
    for (int i = tid; i < NBUCK; i += 256) {
        int c = cnt[i];
        int base = c ? atomicAdd(&bcur[i], c) : 0;     // reserve range in bucket window
        cur[i] = i * CAPG + base;
    }
    __syncthreads();
    for (int i = tid; i < CHUNK; i += 256) {
        int dv = dst[e0 + i], sv = src[e0 + i];
        int b  = dv >> 7;
        int dl = dv & (BSZ - 1);
        int pos = atomicAdd(&cur[b], 1);
        ebuf[pos] = ((unsigned)dl << 24) | (unsigned)sv;
    }
}

// ---------- B4: per-bucket counting sort in LDS, then wave-per-node register agg ----------
__global__ __launch_bounds__(512) void k_bagg2(
        const unsigned* __restrict__ ebuf, const int* __restrict__ bcur,
        const float* __restrict__ s_src, const float* __restrict__ s_dst,
        const bf16* __restrict__ hg, float* __restrict__ agg) {
    __shared__ unsigned sl[CAP];        // 16 KB: src indices in dst-sorted order
    __shared__ int cnt[BSZ];
    __shared__ int sstart[BSZ];
    __shared__ int spos[BSZ];
    __shared__ int sscan[BSZ];
    int tid = threadIdx.x;
    int b = blockIdx.x;
    int rs = b * CAPG;
    int ne = min(bcur[b], CAP);
    for (int i = tid; i < BSZ; i += 512) cnt[i] = 0;
    __syncthreads();
    for (int i = tid; i < ne; i += 512)
        atomicAdd(&cnt[ebuf[rs + i] >> 24], 1);
    __syncthreads();
    int v = (tid < BSZ) ? cnt[tid] : 0;
    if (tid < BSZ) sscan[tid] = v;
    __syncthreads();
    for (int s = 1; s < BSZ; s <<= 1) {
        int add = (tid < BSZ && tid >= s) ? sscan[tid - s] : 0;
        __syncthreads();
        if (tid < BSZ) sscan[tid] += add;
        __syncthreads();
    }
    if (tid < BSZ) { sstart[tid] = sscan[tid] - v; spos[tid] = sscan[tid] - v; }
    __syncthreads();
    for (int i = tid; i < ne; i += 512) {
        unsigned p = ebuf[rs + i];
        int dl = p >> 24;
        int q = atomicAdd(&spos[dl], 1);
        sl[q] = p & 0xFFFFFFu;
    }
    __syncthreads();
    int lane = tid & 63, wv = tid >> 6;
    int lane8 = lane & 7, grp = lane >> 3;
    for (int dl = wv; dl < BSZ; dl += 8) {
        int node = b * BSZ + dl;
        if (node >= NN) break;
        int st = sstart[dl], deg = cnt[dl];
        float sd = s_dst[node];
        float a[8] = {0.f}, denom = 0.f;
        for (int i = grp; i < deg; i += 8) {
            int sv = sl[st + i];
            float s = s_src[sv] + sd;
            s = (s >= 0.f) ? s : 0.2f * s;    // leaky_relu 0.2
            float ex = __expf(s);
            denom += ex;
            uint4 u = *(const uint4*)&hg[(size_t)sv * HH + lane8 * 8];
            float f0, f1, f2, f3, f4, f5, f6, f7;
            bf2x(u.x, f0, f1); bf2x(u.y, f2, f3);
            bf2x(u.z, f4, f5); bf2x(u.w, f6, f7);
            a[0] = fmaf(ex, f0, a[0]); a[1] = fmaf(ex, f1, a[1]);
            a[2] = fmaf(ex, f2, a[2]); a[3] = fmaf(ex, f3, a[3]);
            a[4] = fmaf(ex, f4, a[4]); a[5] = fmaf(ex, f5, a[5]);
            a[6] = fmaf(ex, f6, a[6]); a[7] = fmaf(ex, f7, a[7]);
        }
        #pragma unroll
        for (int off = 8; off < 64; off <<= 1) {
            #pragma unroll
            for (int j = 0; j < 8; j++) a[j] += __shfl_xor(a[j], off);
            denom += __shfl_xor(denom, off);
        }
        if (lane < 8) {
            float inv = 1.f / (denom + 1e-9f);
            float4 r0 = make_float4(a[0] * inv, a[1] * inv, a[2] * inv, a[3] * inv);
            float4 r1 = make_float4(a[4] * inv, a[5] * inv, a[6] * inv, a[7] * inv);
            *(float4*)&agg[(size_t)node * HH + lane8 * 8]     = r0;
            *(float4*)&agg[(size_t)node * HH + lane8 * 8 + 4] = r1;
        }
    }
}

// ---------- K7: xc = relu(agg); node head; bf16 p_src/p_dst partials ----------
__global__ __launch_bounds__(256) void k_nodehead(
        const float* __restrict__ agg,
        const float* __restrict__ Wn1, const float* __restrict__ bn1,
        const float* __restrict__ Wn2, const float* __restrict__ bn2,
        const float* __restrict__ We1,
        bf16* __restrict__ p_src, bf16* __restrict__ p_dst, float* __restrict__ out_node) {
    __shared__ float wn1[HH * HH];
    __shared__ float we1s[HH * HH];
    __shared__ float we1d[HH * HH];
    __shared__ float xbuf[16][HH];
    int tid = threadIdx.x;
    for (int i = tid; i < HH * HH; i += 256) {
        wn1[i]  = Wn1[i];
        we1s[i] = We1[i];
        we1d[i] = We1[HH * HH + i];
    }
    int lane = tid & 63;
    int wv = __builtin_amdgcn_readfirstlane(tid >> 6);
    float bn1l = bn1[lane];
    float wn2a = Wn2[lane * NCLS + 0], wn2b = Wn2[lane * NCLS + 1];
    float bn20 = bn2[0], bn21 = bn2[1];
    __syncthreads();
    for (int base = blockIdx.x * 16; base < NN; base += gridDim.x * 16) {
        int n0 = base + wv * NPW;
        #pragma unroll
        for (int j = 0; j < NPW; j++)
            xbuf[wv * NPW + j][lane] = fmaxf(agg[(size_t)(n0 + j) * HH + lane], 0.f);
        __syncthreads();
        float tn[NPW], ps[NPW], pd[NPW];
        #pragma unroll
        for (int j = 0; j < NPW; j++) { tn[j] = bn1l; ps[j] = 0.f; pd[j] = 0.f; }
        #pragma unroll 4
        for (int k = 0; k < HH; k++) {
            float w1 = wn1[k * HH + lane];
            float ws = we1s[k * HH + lane];
            float wd = we1d[k * HH + lane];
            #pragma unroll
            for (int j = 0; j < NPW; j++) {
                float xv = xbuf[wv * NPW + j][k];
                tn[j] = fmaf(xv, w1, tn[j]);
                ps[j] = fmaf(xv, ws, ps[j]);
                pd[j] = fmaf(xv, wd, pd[j]);
            }
        }
        #pragma unroll
        for (int j = 0; j < NPW; j++) {
            int node = n0 + j;
            p_src[(size_t)node * HH + lane] = __float2bfloat16(ps[j]);
            p_dst[(size_t)node * HH + lane] = __float2bfloat16(pd[j]);
            float r = fmaxf(tn[j], 0.f);
            float l0 = r * wn2a, l1 = r * wn2b;
            #pragma unroll
            for (int off = 32; off; off >>= 1) {
                l0 += __shfl_xor(l0, off);
                l1 += __shfl_xor(l1, off);
            }
            if (lane == 0)
                *(float2*)&out_node[(size_t)node * NCLS] = make_float2(l0 + bn20, l1 + bn21);
        }
        __syncthreads();
    }
}

// ---------- K8: edge head. 16 lanes per edge-pair (2 edges/group/iter), weights in regs.
__global__ __launch_bounds__(256) void k_edgehead(
        const int* __restrict__ src, const int* __restrict__ dst,
        const float* __restrict__ edge_attr,
        const bf16* __restrict__ p_src, const bf16* __restrict__ p_dst,
        const float* __restrict__ We1, const float* __restrict__ be1,
        const float* __restrict__ We2, const float* __restrict__ be2,
        float* __restrict__ out_edge) {
    int tid = threadIdx.x;
    int lane16 = tid & 15;
    int grp    = (tid & 63) >> 4;
    int wave   = tid >> 6;
    float w1a[DEA][4], w2c0[4], w2c1[4], b1v[4];
    #pragma unroll
    for (int d = 0; d < DEA; d++) {
        float4 v = *(const float4*)&We1[(2 * HH + d) * HH + lane16 * 4];
        w1a[d][0] = v.x; w1a[d][1] = v.y; w1a[d][2] = v.z; w1a[d][3] = v.w;
    }
    float4 bv = *(const float4*)&be1[lane16 * 4];
    b1v[0] = bv.x; b1v[1] = bv.y; b1v[2] = bv.z; b1v[3] = bv.w;
    #pragma unroll
    for (int j = 0; j < 4; j++) {
        w2c0[j] = We2[(lane16 * 4 + j) * NCLS + 0];
        w2c1[j] = We2[(lane16 * 4 + j) * NCLS + 1];
    }
    float be20 = be2[0], be21 = be2[1];

    int stride = gridDim.x * 32;   // 32 edges per block-iteration
    for (int e = blockIdx.x * 32 + wave * 8 + grp * 2; e < EE; e += stride) {
        int ea = e, eb = e + 1;
        int sva = src[ea], dva = dst[ea];
        int svb = src[eb], dvb = dst[eb];
        uint2 usa = *(const uint2*)&p_src[(size_t)sva * HH + lane16 * 4];
        uint2 uda = *(const uint2*)&p_dst[(size_t)dva * HH + lane16 * 4];
        uint2 usb = *(const uint2*)&p_src[(size_t)svb * HH + lane16 * 4];
        uint2 udb = *(const uint2*)&p_dst[(size_t)dvb * HH + lane16 * 4];
        float4 aa0 = *(const float4*)&edge_attr[(size_t)ea * DEA];
        float4 aa1 = *(const float4*)&edge_attr[(size_t)ea * DEA + 4];
        float4 ab0 = *(const float4*)&edge_attr[(size_t)eb * DEA];
        float4 ab1 = *(const float4*)&edge_attr[(size_t)eb * DEA + 4];
        float ava[DEA] = {aa0.x, aa0.y, aa0.z, aa0.w, aa1.x, aa1.y, aa1.z, aa1.w};
        float avb[DEA] = {ab0.x, ab0.y, ab0.z, ab0.w, ab1.x, ab1.y, ab1.z, ab1.w};
        float sa0, sa1, sa2, sa3, da0, da1, da2, da3;
        float sb0, sb1, sb2, sb3, db0, db1, db2, db3;
        bf2x(usa.x, sa0, sa1); bf2x(usa.y, sa2, sa3);
        bf2x(uda.x, da0, da1); bf2x(uda.y, da2, da3);
        bf2x(usb.x, sb0, sb1); bf2x(usb.y, sb2, sb3);
        bf2x(udb.x, db0, db1); bf2x(udb.y, db2, db3);
        float ta[4] = {sa0 + da0 + b1v[0], sa1 + da1 + b1v[1],
                       sa2 + da2 + b1v[2], sa3 + da3 + b1v[3]};
        float tb_[4] = {sb0 + db0 + b1v[0], sb1 + db1 + b1v[1],
                        sb2 + db2 + b1v[2], sb3 + db3 + b1v[3]};
        float l0a = 0.f, l1a = 0.f, l0b = 0.f, l1b = 0.f;
        #pragma unroll
        for (int j = 0; j < 4; j++) {
            #pragma unroll
            for (int d = 0; d < DEA; d++) {
                ta[j]  = fmaf(ava[d], w1a[d][j], ta[j]);
                tb_[j] = fmaf(avb[d], w1a[d][j], tb_[j]);
            }
            float ra = fmaxf(ta[j], 0.f), rb = fmaxf(tb_[j], 0.f);
            l0a = fmaf(ra, w2c0[j], l0a); l1a = fmaf(ra, w2c1[j], l1a);
            l0b = fmaf(rb, w2c0[j], l0b); l1b = fmaf(rb, w2c1[j], l1b);
        }
        #pragma unroll
        for (int off = 8; off; off >>= 1) {
            l0a += __shfl_xor(l0a, off); l1a += __shfl_xor(l1a, off);
            l0b += __shfl_xor(l0b, off); l1b += __shfl_xor(l1b, off);
        }
        if (lane16 == 0) {
            *(float2*)&out_edge[(size_t)ea * NCLS] = make_float2(l0a + be20, l1a + be21);
            *(float2*)&out_edge[(size_t)eb * NCLS] = make_float2(l0b + be20, l1b + be21);
        }
    }
}

extern "C" void kernel_launch(void* const* d_in, const int* in_sizes, int n_in,
                              void* d_out, int out_size, void* d_ws, size_t ws_size,
                              hipStream_t stream) {
    const float* x      = (const float*)d_in[0];
    const int*   ei     = (const int*)  d_in[1];
    const float* attr   = (const float*)d_in[2];
    const float* W_enc  = (const float*)d_in[3];
    const float* b_enc  = (const float*)d_in[4];
    const float* W_gat  = (const float*)d_in[5];
    const float* a_src  = (const float*)d_in[6];
    const float* a_dst  = (const float*)d_in[7];
    const float* Wn1    = (const float*)d_in[8];
    const float* bn1    = (const float*)d_in[9];
    const float* Wn2    = (const float*)d_in[10];
    const float* bn2    = (const float*)d_in[11];
    const float* We1    = (const float*)d_in[12];
    const float* be1    = (const float*)d_in[13];
    const float* We2    = (const float*)d_in[14];
    const float* be2    = (const float*)d_in[15];
    float* out = (float*)d_out;
    float* ws  = (float*)d_ws;

    // workspace layout (float units), total ~60 MB:
    bf16*     hg_psrc = (bf16*)ws;                       // [N*H] bf16: hg, later p_src
    float*    agg     = ws + (size_t)NN * 32;            // [N*H] f32
    bf16*     p_dst   = (bf16*)(ws + (size_t)NN * 96);   // [N*H] bf16
    float*    ssrc    = ws + (size_t)NN * 128;           // [N]
    float*    sdst    = ssrc + NN;                       // [N]
    int*      bcur    = (int*)(sdst + NN);               // [NBUCK] count cursors
    unsigned* ebuf    = (unsigned*)(bcur + 1024);        // [NBUCK*CAPG] bucket windows

    const int* srcp = ei;
    const int* dstp = ei + EE;

    hipMemsetAsync(bcur, 0, NBUCK * sizeof(int), stream);
    k_encode  <<<782, 256, 0, stream>>>(x, W_enc, b_enc, W_gat, a_src, a_dst,
                                        hg_psrc, ssrc, sdst);
    k_cscatter<<<NCHUNK, 256, 0, stream>>>(srcp, dstp, bcur, ebuf);
    k_bagg2   <<<NBUCK, 512, 0, stream>>>(ebuf, bcur, ssrc, sdst, hg_psrc, agg);
    k_nodehead<<<2048, 256, 0, stream>>>(agg, Wn1, bn1, Wn2, bn2, We1,
                                         hg_psrc /*p_src*/, p_dst, out);
    k_edgehead<<<8192, 256, 0, stream>>>(srcp, dstp, attr, hg_psrc, p_dst,
                                         We1, be1, We2, be2, out + (size_t)NN * NCLS);
}

// Round 12
// 211.987 us; speedup vs baseline: 6.9031x; 1.2666x over previous
//
#include <hip/hip_runtime.h>
#include <hip/hip_bf16.h>

#define NN   100000
#define EE   1600000
#define DIN  128
#define HH   64
#define DEA  8
#define NCLS 2
#define BSZ  128                  // dst nodes per bucket
#define NBUCK ((NN + BSZ - 1) / BSZ)   // 782
#define CAPG 2368                 // per-bucket window capacity (mean 2046, sd ~45, +7 sigma)
#define CAP  4096                 // per-bucket LDS edge capacity in k_bagg2
#define NCHUNK 100                // scatter blocks; EE/NCHUNK = 16000 edges each, exact
#define CHUNK (EE / NCHUNK)

typedef __hip_bfloat16 bf16;
typedef short  short8 __attribute__((ext_vector_type(8)));
typedef float  f32x4  __attribute__((ext_vector_type(4)));

// unpack uint = two packed bf16 (lo = low 16 bits, hi = high 16 bits)
__device__ __forceinline__ void bf2x(unsigned u, float& lo, float& hi) {
    union { unsigned i; float f; } a, b;
    a.i = u << 16; b.i = u & 0xffff0000u;
    lo = a.f; hi = b.f;
}
// f32 -> bf16 bits, round-to-nearest-even
__device__ __forceinline__ short f2bs(float f) {
    unsigned u = __float_as_uint(f);
    return (short)((u + 0x7fffu + ((u >> 16) & 1u)) >> 16);
}
__device__ __forceinline__ short8 cvt8(float4 a, float4 b) {
    short8 r;
    r[0] = f2bs(a.x); r[1] = f2bs(a.y); r[2] = f2bs(a.z); r[3] = f2bs(a.w);
    r[4] = f2bs(b.x); r[5] = f2bs(b.y); r[6] = f2bs(b.z); r[7] = f2bs(b.w);
    return r;
}
__device__ __forceinline__ f32x4 z4() {
    f32x4 z; z[0] = 0.f; z[1] = 0.f; z[2] = 0.f; z[3] = 0.f; return z;
}

// ---------- K2 (MFMA): h = relu(x@W_enc+b); hg = h@W_gat; s_src/s_dst = hg . a ----------
#define WE_STRIDE 136
#define WG_STRIDE 72
#define TB_STRIDE 68
__global__ __launch_bounds__(256) void k_encode(
        const float* __restrict__ x,
        const float* __restrict__ W_enc, const float* __restrict__ b_enc,
        const float* __restrict__ W_gat,
        const float* __restrict__ a_src, const float* __restrict__ a_dst,
        bf16* __restrict__ hg_, float* __restrict__ s_src, float* __restrict__ s_dst) {
    __shared__ short wencT[64 * WE_STRIDE];   // [n][k] bf16, 17408 B
    __shared__ short wgatT[64 * WG_STRIDE];   // [n][k] bf16,  9216 B
    __shared__ float tb[4][16 * TB_STRIDE];   // per-wave transpose buf, 17408 B
    short* hg = (short*)hg_;
    int tid = threadIdx.x;
    for (int i = tid; i < DIN * HH; i += 256) {
        int k = i >> 6, n = i & 63;
        wencT[n * WE_STRIDE + k] = f2bs(W_enc[i]);
    }
    for (int i = tid; i < HH * HH; i += 256) {
        int k = i >> 6, n = i & 63;
        wgatT[n * WG_STRIDE + k] = f2bs(W_gat[i]);
    }
    __syncthreads();
    int w = tid >> 6, l = tid & 63, m = l & 15, h = l >> 4;
    short8 wg[2][4];
    #pragma unroll
    for (int kt = 0; kt < 2; kt++)
        #pragma unroll
        for (int nt = 0; nt < 4; nt++)
            wg[kt][nt] = *(short8*)&wgatT[(nt * 16 + m) * WG_STRIDE + kt * 32 + h * 8];
    float avs[4], avd[4], ben[4];
    #pragma unroll
    for (int nt = 0; nt < 4; nt++) {
        avs[nt] = a_src[nt * 16 + m];
        avd[nt] = a_dst[nt * 16 + m];
        ben[nt] = b_enc[nt * 16 + m];
    }
    int tp = blockIdx.x * 4 + w;
    if (tp >= NN / 32) return;
    int n0 = tp * 32;
    float* tbw = tb[w];

    f32x4 acc1[2][4];
    #pragma unroll
    for (int rt = 0; rt < 2; rt++)
        #pragma unroll
        for (int nt = 0; nt < 4; nt++) acc1[rt][nt] = z4();
    #pragma unroll
    for (int kt = 0; kt < 4; kt++) {
        short8 af[2];
        #pragma unroll
        for (int rt = 0; rt < 2; rt++) {
            const float* xp = &x[(size_t)(n0 + rt * 16 + m) * DIN + kt * 32 + h * 8];
            af[rt] = cvt8(*(const float4*)xp, *(const float4*)(xp + 4));
        }
        #pragma unroll
        for (int nt = 0; nt < 4; nt++) {
            short8 bf = *(short8*)&wencT[(nt * 16 + m) * WE_STRIDE + kt * 32 + h * 8];
            acc1[0][nt] = __builtin_amdgcn_mfma_f32_16x16x32_bf16(af[0], bf, acc1[0][nt], 0, 0, 0);
            acc1[1][nt] = __builtin_amdgcn_mfma_f32_16x16x32_bf16(af[1], bf, acc1[1][nt], 0, 0, 0);
        }
    }
    #pragma unroll
    for (int rt = 0; rt < 2; rt++) {
        #pragma unroll
        for (int nt = 0; nt < 4; nt++)
            #pragma unroll
            for (int r = 0; r < 4; r++) {
                float hv = fmaxf(acc1[rt][nt][r] + ben[nt], 0.f);
                tbw[(h * 4 + r) * TB_STRIDE + nt * 16 + m] = hv;
            }
        f32x4 acc2[4];
        #pragma unroll
        for (int nt = 0; nt < 4; nt++) acc2[nt] = z4();
        #pragma unroll
        for (int kt = 0; kt < 2; kt++) {
            const float* tp_ = &tbw[m * TB_STRIDE + kt * 32 + h * 8];
            short8 af2 = cvt8(*(const float4*)tp_, *(const float4*)(tp_ + 4));
            #pragma unroll
            for (int nt = 0; nt < 4; nt++)
                acc2[nt] = __builtin_amdgcn_mfma_f32_16x16x32_bf16(af2, wg[kt][nt], acc2[nt], 0, 0, 0);
        }
        float ps[4] = {0.f, 0.f, 0.f, 0.f}, pd[4] = {0.f, 0.f, 0.f, 0.f};
        #pragma unroll
        for (int nt = 0; nt < 4; nt++)
            #pragma unroll
            for (int r = 0; r < 4; r++) {
                float v = acc2[nt][r];
                ps[r] = fmaf(v, avs[nt], ps[r]);
                pd[r] = fmaf(v, avd[nt], pd[r]);
                hg[(size_t)(n0 + rt * 16 + h * 4 + r) * HH + nt * 16 + m] = f2bs(v);
            }
        #pragma unroll
        for (int off = 1; off < 16; off <<= 1)
            #pragma unroll
            for (int r = 0; r < 4; r++) {
                ps[r] += __shfl_xor(ps[r], off);
                pd[r] += __shfl_xor(pd[r], off);
            }
        if (m == 0) {
            *(float4*)&s_src[n0 + rt * 16 + h * 4] = make_float4(ps[0], ps[1], ps[2], ps[3]);
            *(float4*)&s_dst[n0 + rt * 16 + h * 4] = make_float4(pd[0], pd[1], pd[2], pd[3]);
        }
    }
}

// ---------- B3': two-level scatter, 1024 thr/block (same 100 blocks -> atomic depth 100).
__global__ __launch_bounds__(1024) void k_cscatter(
        const int* __restrict__ src, const int* __restrict__ dst,
        int* bcur, unsigned* __restrict__ ebuf) {
    __shared__ int cnt[NBUCK];
    __shared__ int cur[NBUCK];
    int tid = threadIdx.x;
    int e0 = blockIdx.x * CHUNK;
    for (int i = tid; i < NBUCK; i += 1024) cnt[i] = 0;
    __syncthreads();
    for (int i = tid; i < CHUNK; i += 1024)
        atomicAdd(&cnt[dst[e0 + i] >> 7], 1);          // BSZ = 128
    __syncthreads();
    for (int i = tid; i < NBUCK; i += 1024) {
        int c = cnt[i];
        int base = c ? atomicAdd(&bcur[i], c) : 0;     // reserve range in bucket window
        cur[i] = i * CAPG + base;
    }
    __syncthreads();
    for (int i = tid; i < CHUNK; i += 1024) {
        int dv = dst[e0 + i], sv = src[e0 + i];
        int b  = dv >> 7;
        int dl = dv & (BSZ - 1);
        int pos = atomicAdd(&cur[b], 1);
        ebuf[pos] = ((unsigned)dl << 24) | (unsigned)sv;
    }
}

// ---------- B4: per-bucket counting sort in LDS, then wave-per-node register agg ----------
__global__ __launch_bounds__(512) void k_bagg2(
        const unsigned* __restrict__ ebuf, const int* __restrict__ bcur,
        const float* __restrict__ s_src, const float* __restrict__ s_dst,
        const bf16* __restrict__ hg, float* __restrict__ agg) {
    __shared__ unsigned sl[CAP];
    __shared__ int cnt[BSZ];
    __shared__ int sstart[BSZ];
    __shared__ int spos[BSZ];
    __shared__ int sscan[BSZ];
    int tid = threadIdx.x;
    int b = blockIdx.x;
    int rs = b * CAPG;
    int ne = min(bcur[b], CAP);
    for (int i = tid; i < BSZ; i += 512) cnt[i] = 0;
    __syncthreads();
    for (int i = tid; i < ne; i += 512)
        atomicAdd(&cnt[ebuf[rs + i] >> 24], 1);
    __syncthreads();
    int v = (tid < BSZ) ? cnt[tid] : 0;
    if (tid < BSZ) sscan[tid] = v;
    __syncthreads();
    for (int s = 1; s < BSZ; s <<= 1) {
        int add = (tid < BSZ && tid >= s) ? sscan[tid - s] : 0;
        __syncthreads();
        if (tid < BSZ) sscan[tid] += add;
        __syncthreads();
    }
    if (tid < BSZ) { sstart[tid] = sscan[tid] - v; spos[tid] = sscan[tid] - v; }
    __syncthreads();
    for (int i = tid; i < ne; i += 512) {
        unsigned p = ebuf[rs + i];
        int dl = p >> 24;
        int q = atomicAdd(&spos[dl], 1);
        sl[q] = p & 0xFFFFFFu;
    }
    __syncthreads();
    int lane = tid & 63, wv = tid >> 6;
    int lane8 = lane & 7, grp = lane >> 3;
    for (int dl = wv; dl < BSZ; dl += 8) {
        int node = b * BSZ + dl;
        if (node >= NN) break;
        int st = sstart[dl], deg = cnt[dl];
        float sd = s_dst[node];
        float a[8] = {0.f}, denom = 0.f;
        for (int i = grp; i < deg; i += 8) {
            int sv = sl[st + i];
            float s = s_src[sv] + sd;
            s = (s >= 0.f) ? s : 0.2f * s;    // leaky_relu 0.2
            float ex = __expf(s);
            denom += ex;
            uint4 u = *(const uint4*)&hg[(size_t)sv * HH + lane8 * 8];
            float f0, f1, f2, f3, f4, f5, f6, f7;
            bf2x(u.x, f0, f1); bf2x(u.y, f2, f3);
            bf2x(u.z, f4, f5); bf2x(u.w, f6, f7);
            a[0] = fmaf(ex, f0, a[0]); a[1] = fmaf(ex, f1, a[1]);
            a[2] = fmaf(ex, f2, a[2]); a[3] = fmaf(ex, f3, a[3]);
            a[4] = fmaf(ex, f4, a[4]); a[5] = fmaf(ex, f5, a[5]);
            a[6] = fmaf(ex, f6, a[6]); a[7] = fmaf(ex, f7, a[7]);
        }
        #pragma unroll
        for (int off = 8; off < 64; off <<= 1) {
            #pragma unroll
            for (int j = 0; j < 8; j++) a[j] += __shfl_xor(a[j], off);
            denom += __shfl_xor(denom, off);
        }
        if (lane < 8) {
            float inv = 1.f / (denom + 1e-9f);
            float4 r0 = make_float4(a[0] * inv, a[1] * inv, a[2] * inv, a[3] * inv);
            float4 r1 = make_float4(a[4] * inv, a[5] * inv, a[6] * inv, a[7] * inv);
            *(float4*)&agg[(size_t)node * HH + lane8 * 8]     = r0;
            *(float4*)&agg[(size_t)node * HH + lane8 * 8 + 4] = r1;
        }
    }
}

// ---------- K7 (MFMA): xc=relu(agg); [xc]@[Wn1|We1s|We1d] (64->192), node logits + bf16 partials.
#define WC_STRIDE 72
__global__ __launch_bounds__(256) void k_nodehead(
        const float* __restrict__ agg,
        const float* __restrict__ Wn1, const float* __restrict__ bn1,
        const float* __restrict__ Wn2, const float* __restrict__ bn2,
        const float* __restrict__ We1,
        bf16* __restrict__ p_src_, bf16* __restrict__ p_dst_, float* __restrict__ out_node) {
    __shared__ short wcatT[192 * WC_STRIDE];   // 27648 B
    short* p_src = (short*)p_src_;
    short* p_dst = (short*)p_dst_;
    int tid = threadIdx.x;
    for (int i = tid; i < 3 * HH * HH; i += 256) {
        int mat = i >> 12, j = i & 4095;
        int k = j >> 6, l2 = j & 63;
        float v = (mat == 0) ? Wn1[j] : (mat == 1 ? We1[j] : We1[HH * HH + j]);
        wcatT[(mat * 64 + l2) * WC_STRIDE + k] = f2bs(v);
    }
    __syncthreads();
    int w = tid >> 6, l = tid & 63, m = l & 15, h = l >> 4;
    int tp = blockIdx.x * 4 + w;
    if (tp >= NN / 32) return;
    int n0 = tp * 32;
    float ben[4], wn2a[4], wn2b[4];
    #pragma unroll
    for (int nt = 0; nt < 4; nt++) {
        ben[nt]  = bn1[nt * 16 + m];
        wn2a[nt] = Wn2[(nt * 16 + m) * NCLS + 0];
        wn2b[nt] = Wn2[(nt * 16 + m) * NCLS + 1];
    }
    float bn20 = bn2[0], bn21 = bn2[1];
    #pragma unroll
    for (int rt = 0; rt < 2; rt++) {
        f32x4 acc[12];
        #pragma unroll
        for (int nt = 0; nt < 12; nt++) acc[nt] = z4();
        #pragma unroll
        for (int kt = 0; kt < 2; kt++) {
            const float* ap = &agg[(size_t)(n0 + rt * 16 + m) * HH + kt * 32 + h * 8];
            float4 a0 = *(const float4*)ap, a1 = *(const float4*)(ap + 4);
            a0.x = fmaxf(a0.x, 0.f); a0.y = fmaxf(a0.y, 0.f);
            a0.z = fmaxf(a0.z, 0.f); a0.w = fmaxf(a0.w, 0.f);
            a1.x = fmaxf(a1.x, 0.f); a1.y = fmaxf(a1.y, 0.f);
            a1.z = fmaxf(a1.z, 0.f); a1.w = fmaxf(a1.w, 0.f);
            short8 af = cvt8(a0, a1);
            #pragma unroll
            for (int nt = 0; nt < 12; nt++) {
                short8 bf = *(short8*)&wcatT[(nt * 16 + m) * WC_STRIDE + kt * 32 + h * 8];
                acc[nt] = __builtin_amdgcn_mfma_f32_16x16x32_bf16(af, bf, acc[nt], 0, 0, 0);
            }
        }
        // nt 0..3: node-logits path
        float l0[4] = {0.f, 0.f, 0.f, 0.f}, l1[4] = {0.f, 0.f, 0.f, 0.f};
        #pragma unroll
        for (int nt = 0; nt < 4; nt++)
            #pragma unroll
            for (int r = 0; r < 4; r++) {
                float t = fmaxf(acc[nt][r] + ben[nt], 0.f);
                l0[r] = fmaf(t, wn2a[nt], l0[r]);
                l1[r] = fmaf(t, wn2b[nt], l1[r]);
            }
        // nt 4..7: p_src, nt 8..11: p_dst
        #pragma unroll
        for (int nt = 0; nt < 4; nt++)
            #pragma unroll
            for (int r = 0; r < 4; r++) {
                size_t row = (size_t)(n0 + rt * 16 + h * 4 + r) * HH + nt * 16 + m;
                p_src[row] = f2bs(acc[nt + 4][r]);
                p_dst[row] = f2bs(acc[nt + 8][r]);
            }
        #pragma unroll
        for (int off = 1; off < 16; off <<= 1)
            #pragma unroll
            for (int r = 0; r < 4; r++) {
                l0[r] += __shfl_xor(l0[r], off);
                l1[r] += __shfl_xor(l1[r], off);
            }
        if (m == 0) {
            #pragma unroll
            for (int r = 0; r < 4; r++)
                *(float2*)&out_node[(size_t)(n0 + rt * 16 + h * 4 + r) * NCLS] =
                    make_float2(l0[r] + bn20, l1[r] + bn21);
        }
    }
}

// ---------- K8: edge head. 16 lanes per 4-edge group (4 gathers in flight), weights in regs.
__global__ __launch_bounds__(256) void k_edgehead(
        const int* __restrict__ src, const int* __restrict__ dst,
        const float* __restrict__ edge_attr,
        const bf16* __restrict__ p_src, const bf16* __restrict__ p_dst,
        const float* __restrict__ We1, const float* __restrict__ be1,
        const float* __restrict__ We2, const float* __restrict__ be2,
        float* __restrict__ out_edge) {
    int tid = threadIdx.x;
    int lane16 = tid & 15;
    int grp    = (tid & 63) >> 4;
    int wave   = tid >> 6;
    float w1a[DEA][4], w2c0[4], w2c1[4], b1v[4];
    #pragma unroll
    for (int d = 0; d < DEA; d++) {
        float4 v = *(const float4*)&We1[(2 * HH + d) * HH + lane16 * 4];
        w1a[d][0] = v.x; w1a[d][1] = v.y; w1a[d][2] = v.z; w1a[d][3] = v.w;
    }
    float4 bv = *(const float4*)&be1[lane16 * 4];
    b1v[0] = bv.x; b1v[1] = bv.y; b1v[2] = bv.z; b1v[3] = bv.w;
    #pragma unroll
    for (int j = 0; j < 4; j++) {
        w2c0[j] = We2[(lane16 * 4 + j) * NCLS + 0];
        w2c1[j] = We2[(lane16 * 4 + j) * NCLS + 1];
    }
    float be20 = be2[0], be21 = be2[1];

    int stride = gridDim.x * 64;   // 64 edges per block-iteration; EE%64==0
    for (int e = blockIdx.x * 64 + wave * 16 + grp * 4; e < EE; e += stride) {
        int sv[4], dv[4];
        #pragma unroll
        for (int q = 0; q < 4; q++) { sv[q] = src[e + q]; dv[q] = dst[e + q]; }
        uint2 us[4], ud[4];
        float4 at0[4], at1[4];
        #pragma unroll
        for (int q = 0; q < 4; q++) {
            us[q]  = *(const uint2*)&p_src[(size_t)sv[q] * HH + lane16 * 4];
            ud[q]  = *(const uint2*)&p_dst[(size_t)dv[q] * HH + lane16 * 4];
            at0[q] = *(const float4*)&edge_attr[(size_t)(e + q) * DEA];
            at1[q] = *(const float4*)&edge_attr[(size_t)(e + q) * DEA + 4];
        }
        float l0[4], l1[4];
        #pragma unroll
        for (int q = 0; q < 4; q++) {
            float s0, s1, s2, s3, d0, d1, d2, d3;
            bf2x(us[q].x, s0, s1); bf2x(us[q].y, s2, s3);
            bf2x(ud[q].x, d0, d1); bf2x(ud[q].y, d2, d3);
            float t[4] = {s0 + d0 + b1v[0], s1 + d1 + b1v[1],
                          s2 + d2 + b1v[2], s3 + d3 + b1v[3]};
            float av[DEA] = {at0[q].x, at0[q].y, at0[q].z, at0[q].w,
                             at1[q].x, at1[q].y, at1[q].z, at1[q].w};
            l0[q] = 0.f; l1[q] = 0.f;
            #pragma unroll
            for (int j = 0; j < 4; j++) {
                #pragma unroll
                for (int d = 0; d < DEA; d++) t[j] = fmaf(av[d], w1a[d][j], t[j]);
                float r = fmaxf(t[j], 0.f);
                l0[q] = fmaf(r, w2c0[j], l0[q]);
                l1[q] = fmaf(r, w2c1[j], l1[q]);
            }
        }
        #pragma unroll
        for (int off = 8; off; off >>= 1)
            #pragma unroll
            for (int q = 0; q < 4; q++) {
                l0[q] += __shfl_xor(l0[q], off);
                l1[q] += __shfl_xor(l1[q], off);
            }
        if (lane16 == 0) {
            #pragma unroll
            for (int q = 0; q < 4; q++)
                *(float2*)&out_edge[(size_t)(e + q) * NCLS] =
                    make_float2(l0[q] + be20, l1[q] + be21);
        }
    }
}

extern "C" void kernel_launch(void* const* d_in, const int* in_sizes, int n_in,
                              void* d_out, int out_size, void* d_ws, size_t ws_size,
                              hipStream_t stream) {
    const float* x      = (const float*)d_in[0];
    const int*   ei     = (const int*)  d_in[1];
    const float* attr   = (const float*)d_in[2];
    const float* W_enc  = (const float*)d_in[3];
    const float* b_enc  = (const float*)d_in[4];
    const float* W_gat  = (const float*)d_in[5];
    const float* a_src  = (const float*)d_in[6];
    const float* a_dst  = (const float*)d_in[7];
    const float* Wn1    = (const float*)d_in[8];
    const float* bn1    = (const float*)d_in[9];
    const float* Wn2    = (const float*)d_in[10];
    const float* bn2    = (const float*)d_in[11];
    const float* We1    = (const float*)d_in[12];
    const float* be1    = (const float*)d_in[13];
    const float* We2    = (const float*)d_in[14];
    const float* be2    = (const float*)d_in[15];
    float* out = (float*)d_out;
    float* ws  = (float*)d_ws;

    // workspace layout (float units), total ~60 MB:
    bf16*     hg_psrc = (bf16*)ws;                       // [N*H] bf16: hg, later p_src
    float*    agg     = ws + (size_t)NN * 32;            // [N*H] f32
    bf16*     p_dst   = (bf16*)(ws + (size_t)NN * 96);   // [N*H] bf16
    float*    ssrc    = ws + (size_t)NN * 128;           // [N]
    float*    sdst    = ssrc + NN;                       // [N]
    int*      bcur    = (int*)(sdst + NN);               // [NBUCK] count cursors
    unsigned* ebuf    = (unsigned*)(bcur + 1024);        // [NBUCK*CAPG] bucket windows

    const int* srcp = ei;
    const int* dstp = ei + EE;

    hipMemsetAsync(bcur, 0, NBUCK * sizeof(int), stream);
    k_encode  <<<782, 256, 0, stream>>>(x, W_enc, b_enc, W_gat, a_src, a_dst,
                                        hg_psrc, ssrc, sdst);
    k_cscatter<<<NCHUNK, 1024, 0, stream>>>(srcp, dstp, bcur, ebuf);
    k_bagg2   <<<NBUCK, 512, 0, stream>>>(ebuf, bcur, ssrc, sdst, hg_psrc, agg);
    k_nodehead<<<782, 256, 0, stream>>>(agg, Wn1, bn1, Wn2, bn2, We1,
                                        hg_psrc /*p_src*/, p_dst, out);
    k_edgehead<<<8192, 256, 0, stream>>>(srcp, dstp, attr, hg_psrc, p_dst,
                                         We1, be1, We2, be2, out + (size_t)NN * NCLS);
}